// Round 2
// baseline (995.105 us; speedup 1.0000x reference)
//
#include <hip/hip_runtime.h>
#include <hip/hip_bf16.h>

// ---------------- types / constants ----------------
typedef __bf16 bf16_t;
typedef __bf16 bf16x8 __attribute__((ext_vector_type(8)));
typedef float f32x4 __attribute__((ext_vector_type(4)));

#define T_TOK 8192
#define D_IN  2048
#define D_BOT 512
#define NEXP  8
#define N2    4608   // 9 slots * 512 bottleneck
#define K3    4608

union U4B8 { uint4 u; bf16x8 b; };
__device__ __forceinline__ bf16x8 as_bf16x8(uint4 u) { U4B8 x; x.u = u; return x.b; }
__device__ __forceinline__ uint4 as_uint4(bf16x8 b) { U4B8 x; x.b = b; return x.u; }

// load 8 consecutive f32, round to bf16x8
__device__ __forceinline__ uint4 ld_cvt8(const float* __restrict__ p) {
    f32x4 a0 = ((const f32x4*)p)[0];
    f32x4 a1 = ((const f32x4*)p)[1];
    bf16x8 v;
    v[0] = (bf16_t)a0[0]; v[1] = (bf16_t)a0[1]; v[2] = (bf16_t)a0[2]; v[3] = (bf16_t)a0[3];
    v[4] = (bf16_t)a1[0]; v[5] = (bf16_t)a1[1]; v[6] = (bf16_t)a1[2]; v[7] = (bf16_t)a1[3];
    return as_uint4(v);
}

__device__ __forceinline__ float gelu_f(float v) {
    return 0.5f * v * (1.0f + erff(v * 0.7071067811865476f));
}

// ---------------- gate + routing (all f32) ----------------
// one wave per token; combine[t*8+e] = renormalized top-2 softmax weight (0 otherwise)
__global__ __launch_bounds__(256) void gate_kernel(const float* __restrict__ x,
                                                   const float* __restrict__ gw,
                                                   float* __restrict__ combine) {
    const int wave = threadIdx.x >> 6, lane = threadIdx.x & 63;
    const int t = blockIdx.x * 4 + wave;
    const float* xrow = x + (size_t)t * D_IN;
    float xr[32];
#pragma unroll
    for (int i = 0; i < 32; ++i) xr[i] = xrow[lane + (i << 6)];
    float p[8];
#pragma unroll
    for (int e = 0; e < 8; ++e) {
        const float* gr = gw + e * D_IN;
        float s = 0.f;
#pragma unroll
        for (int i = 0; i < 32; ++i) s += xr[i] * gr[lane + (i << 6)];
#pragma unroll
        for (int off = 32; off > 0; off >>= 1) s += __shfl_xor(s, off, 64);
        p[e] = s;
    }
    float m = p[0];
#pragma unroll
    for (int e = 1; e < 8; ++e) m = fmaxf(m, p[e]);
    float sum = 0.f;
#pragma unroll
    for (int e = 0; e < 8; ++e) { p[e] = expf(p[e] - m); sum += p[e]; }
    const float inv = 1.0f / sum;
#pragma unroll
    for (int e = 0; e < 8; ++e) p[e] *= inv;
    int i0 = 0;
#pragma unroll
    for (int e = 1; e < 8; ++e) if (p[e] > p[i0]) i0 = e;
    int i1 = -1;
#pragma unroll
    for (int e = 0; e < 8; ++e) { if (e == i0) continue; if (i1 < 0 || p[e] > p[i1]) i1 = e; }
    const float rs = 1.0f / (p[i0] + p[i1]);
    if (lane < 8)
        combine[t * 8 + lane] = (lane == i0) ? p[i0] * rs : (lane == i1) ? p[i1] * rs : 0.0f;
}

// ---------------- phase 2: H = gelu(X @ Wall^T + bias) * scale ----------------
// M=8192, N=4608, K=2048.  Rows n<4096 -> wd flat; n>=4096 -> ws_d. f32 in, bf16 out.
__global__ __launch_bounds__(256) void down_kernel(const float* __restrict__ X,
                                                   const float* __restrict__ Wd,
                                                   const float* __restrict__ Wsd,
                                                   const float* __restrict__ Bd,
                                                   const float* __restrict__ Bsd,
                                                   const float* __restrict__ combine,
                                                   bf16_t* __restrict__ H) {
    __shared__ uint4 As4[128 * 9];
    __shared__ uint4 Bs4[128 * 9];
    const int tid = threadIdx.x;
    const int lane = tid & 63, wv = tid >> 6;
    const int wm = wv >> 1, wn = wv & 1;
    const int tile_m = blockIdx.y * 128, tile_n = blockIdx.x * 128;
    const int ldr = tid >> 3, ldc = tid & 7;

    f32x4 acc[4][4];
#pragma unroll
    for (int i = 0; i < 4; ++i)
#pragma unroll
        for (int j = 0; j < 4; ++j) acc[i][j] = (f32x4){0.f, 0.f, 0.f, 0.f};

    for (int kt = 0; kt < D_IN / 64; ++kt) {
        const int k0 = kt * 64;
#pragma unroll
        for (int i = 0; i < 4; ++i) {
            const int r = i * 32 + ldr;
            const float* ap = X + (size_t)(tile_m + r) * D_IN + k0 + ldc * 8;
            As4[r * 9 + ldc] = ld_cvt8(ap);
            const int n = tile_n + r;
            const float* bp = (n < 4096 ? Wd + (size_t)n * D_IN
                                        : Wsd + (size_t)(n - 4096) * D_IN) + k0 + ldc * 8;
            Bs4[r * 9 + ldc] = ld_cvt8(bp);
        }
        __syncthreads();
#pragma unroll
        for (int ks = 0; ks < 2; ++ks) {
            bf16x8 af[4], bfr[4];
#pragma unroll
            for (int i = 0; i < 4; ++i) {
                const int ar = wm * 64 + i * 16 + (lane & 15);
                af[i] = as_bf16x8(As4[ar * 9 + ks * 4 + (lane >> 4)]);
                const int br = wn * 64 + i * 16 + (lane & 15);
                bfr[i] = as_bf16x8(Bs4[br * 9 + ks * 4 + (lane >> 4)]);
            }
#pragma unroll
            for (int mi = 0; mi < 4; ++mi)
#pragma unroll
                for (int nj = 0; nj < 4; ++nj)
                    acc[mi][nj] = __builtin_amdgcn_mfma_f32_16x16x32_bf16(
                        af[mi], bfr[nj], acc[mi][nj], 0, 0, 0);
        }
        __syncthreads();
    }

#pragma unroll
    for (int nj = 0; nj < 4; ++nj) {
        const int n = tile_n + wn * 64 + nj * 16 + (lane & 15);
        const int slot = n >> 9;
        const float bias = (n < 4096 ? Bd[n] : Bsd[n - 4096]);
#pragma unroll
        for (int mi = 0; mi < 4; ++mi) {
            const int m0 = tile_m + wm * 64 + mi * 16 + ((lane >> 4) << 2);
#pragma unroll
            for (int r = 0; r < 4; ++r) {
                const int t = m0 + r;
                float v = gelu_f(acc[mi][nj][r] + bias);
                const float sc = (slot < 8) ? combine[t * 8 + slot] : 1.0f;
                H[(size_t)t * N2 + n] = (bf16_t)(v * sc);
            }
        }
    }
}

// ---------------- phase 3: Out = H @ WuAll^T + combine@bu + bs_u ----------------
// M=8192, N=2048, K=4608.  k-slot s<8 -> wu[s], s==8 -> ws_u. H bf16, weights f32, out f32.
__global__ __launch_bounds__(256) void up_kernel(const bf16_t* __restrict__ H,
                                                 const float* __restrict__ Wu,
                                                 const float* __restrict__ Wsu,
                                                 const float* __restrict__ Bu,
                                                 const float* __restrict__ Bsu,
                                                 const float* __restrict__ combine,
                                                 float* __restrict__ Out) {
    __shared__ uint4 As4[128 * 9];
    __shared__ uint4 Bs4[128 * 9];
    const int tid = threadIdx.x;
    const int lane = tid & 63, wv = tid >> 6;
    const int wm = wv >> 1, wn = wv & 1;
    const int tile_m = blockIdx.y * 128, tile_n = blockIdx.x * 128;
    const int ldr = tid >> 3, ldc = tid & 7;

    f32x4 acc[4][4];
#pragma unroll
    for (int i = 0; i < 4; ++i)
#pragma unroll
        for (int j = 0; j < 4; ++j) acc[i][j] = (f32x4){0.f, 0.f, 0.f, 0.f};

    for (int kt = 0; kt < K3 / 64; ++kt) {
        const int k0 = kt * 64;
        const int slot = k0 >> 9;
        const int b0 = k0 & 511;
        const float* wbase = (slot < 8) ? Wu + (size_t)slot * (D_IN * D_BOT) : Wsu;
#pragma unroll
        for (int i = 0; i < 4; ++i) {
            const int r = i * 32 + ldr;
            const bf16_t* ap = H + (size_t)(tile_m + r) * K3 + k0 + ldc * 8;
            As4[r * 9 + ldc] = *(const uint4*)ap;          // H already bf16
            const int n = tile_n + r;
            const float* bp = wbase + (size_t)n * D_BOT + b0 + ldc * 8;
            Bs4[r * 9 + ldc] = ld_cvt8(bp);
        }
        __syncthreads();
#pragma unroll
        for (int ks = 0; ks < 2; ++ks) {
            bf16x8 af[4], bfr[4];
#pragma unroll
            for (int i = 0; i < 4; ++i) {
                const int ar = wm * 64 + i * 16 + (lane & 15);
                af[i] = as_bf16x8(As4[ar * 9 + ks * 4 + (lane >> 4)]);
                const int br = wn * 64 + i * 16 + (lane & 15);
                bfr[i] = as_bf16x8(Bs4[br * 9 + ks * 4 + (lane >> 4)]);
            }
#pragma unroll
            for (int mi = 0; mi < 4; ++mi)
#pragma unroll
                for (int nj = 0; nj < 4; ++nj)
                    acc[mi][nj] = __builtin_amdgcn_mfma_f32_16x16x32_bf16(
                        af[mi], bfr[nj], acc[mi][nj], 0, 0, 0);
        }
        __syncthreads();
    }

#pragma unroll
    for (int nj = 0; nj < 4; ++nj) {
        const int d = tile_n + wn * 64 + nj * 16 + (lane & 15);
        float buv[8];
#pragma unroll
        for (int e = 0; e < 8; ++e) buv[e] = Bu[e * D_IN + d];
        const float bsu = Bsu[d];
#pragma unroll
        for (int mi = 0; mi < 4; ++mi) {
            const int m0 = tile_m + wm * 64 + mi * 16 + ((lane >> 4) << 2);
#pragma unroll
            for (int r = 0; r < 4; ++r) {
                const int t = m0 + r;
                float v = acc[mi][nj][r] + bsu;
                const float* cr = combine + t * 8;
#pragma unroll
                for (int e = 0; e < 8; ++e) v += cr[e] * buv[e];
                Out[(size_t)t * D_IN + d] = v;
            }
        }
    }
}

// ---------------- launch ----------------
extern "C" void kernel_launch(void* const* d_in, const int* in_sizes, int n_in,
                              void* d_out, int out_size, void* d_ws, size_t ws_size,
                              hipStream_t stream) {
    const float* x   = (const float*)d_in[0];
    const float* gw  = (const float*)d_in[1];
    const float* wd  = (const float*)d_in[2];
    const float* bd  = (const float*)d_in[3];
    const float* wu  = (const float*)d_in[4];
    const float* bu  = (const float*)d_in[5];
    const float* wsd = (const float*)d_in[6];
    const float* bsd = (const float*)d_in[7];
    const float* wsu = (const float*)d_in[8];
    const float* bsu = (const float*)d_in[9];
    float* out = (float*)d_out;

    float* combine = (float*)d_ws;                                  // 8192*8*4 = 256 KB
    bf16_t* H = (bf16_t*)((char*)d_ws + (size_t)T_TOK * 8 * 4);     // 8192*4608*2 = 75.5 MB

    gate_kernel<<<T_TOK / 4, 256, 0, stream>>>(x, gw, combine);
    down_kernel<<<dim3(N2 / 128, T_TOK / 128), 256, 0, stream>>>(x, wd, wsd, bd, bsd, combine, H);
    up_kernel<<<dim3(D_IN / 128, T_TOK / 128), 256, 0, stream>>>(H, wu, wsu, bu, bsu, combine, out);
}

// Round 3
// 840.588 us; speedup vs baseline: 1.1838x; 1.1838x over previous
//
#include <hip/hip_runtime.h>
#include <hip/hip_bf16.h>

// ---------------- types / constants ----------------
typedef __bf16 bf16_t;
typedef __bf16 bf16x8 __attribute__((ext_vector_type(8)));
typedef float f32x4 __attribute__((ext_vector_type(4)));

#define T_TOK 8192
#define D_IN  2048
#define D_BOT 512
#define N2    4608   // 9 slots * 512 bottleneck
#define K3    4608

union U4B8 { uint4 u; bf16x8 b; };
__device__ __forceinline__ bf16x8 as_bf16x8(uint4 u) { U4B8 x; x.u = u; return x.b; }
__device__ __forceinline__ uint4 as_uint4(bf16x8 b) { U4B8 x; x.b = b; return x.u; }

// async 16B global->LDS (lane l lands at ldsbase + 16*l)
typedef const __attribute__((address_space(1))) void gas_void;
typedef __attribute__((address_space(3))) void las_void;
__device__ __forceinline__ void async16(const void* g, void* l) {
    __builtin_amdgcn_global_load_lds((gas_void*)g, (las_void*)l, 16, 0, 0);
}

// load 8 consecutive f32, round to bf16x8
__device__ __forceinline__ uint4 ld_cvt8(const float* __restrict__ p) {
    f32x4 a0 = ((const f32x4*)p)[0];
    f32x4 a1 = ((const f32x4*)p)[1];
    bf16x8 v;
    v[0] = (bf16_t)a0[0]; v[1] = (bf16_t)a0[1]; v[2] = (bf16_t)a0[2]; v[3] = (bf16_t)a0[3];
    v[4] = (bf16_t)a1[0]; v[5] = (bf16_t)a1[1]; v[6] = (bf16_t)a1[2]; v[7] = (bf16_t)a1[3];
    return as_uint4(v);
}

__device__ __forceinline__ float gelu_f(float v) {
    return 0.5f * v * (1.0f + erff(v * 0.7071067811865476f));
}

// ---------------- f32 -> bf16 bulk convert (8 elems/thread) ----------------
__global__ __launch_bounds__(256) void cvt_kernel(const float* __restrict__ src,
                                                  bf16_t* __restrict__ dst, int n8) {
    const int i = blockIdx.x * 256 + threadIdx.x;
    if (i < n8) ((uint4*)dst)[i] = ld_cvt8(src + (size_t)i * 8);
}

// ---------------- gate + routing (all f32) ----------------
__global__ __launch_bounds__(256) void gate_kernel(const float* __restrict__ x,
                                                   const float* __restrict__ gw,
                                                   float* __restrict__ combine) {
    const int wave = threadIdx.x >> 6, lane = threadIdx.x & 63;
    const int t = blockIdx.x * 4 + wave;
    const float* xrow = x + (size_t)t * D_IN;
    float xr[32];
#pragma unroll
    for (int i = 0; i < 32; ++i) xr[i] = xrow[lane + (i << 6)];
    float p[8];
#pragma unroll
    for (int e = 0; e < 8; ++e) {
        const float* gr = gw + e * D_IN;
        float s = 0.f;
#pragma unroll
        for (int i = 0; i < 32; ++i) s += xr[i] * gr[lane + (i << 6)];
#pragma unroll
        for (int off = 32; off > 0; off >>= 1) s += __shfl_xor(s, off, 64);
        p[e] = s;
    }
    float m = p[0];
#pragma unroll
    for (int e = 1; e < 8; ++e) m = fmaxf(m, p[e]);
    float sum = 0.f;
#pragma unroll
    for (int e = 0; e < 8; ++e) { p[e] = expf(p[e] - m); sum += p[e]; }
    const float inv = 1.0f / sum;
#pragma unroll
    for (int e = 0; e < 8; ++e) p[e] *= inv;
    int i0 = 0;
#pragma unroll
    for (int e = 1; e < 8; ++e) if (p[e] > p[i0]) i0 = e;
    int i1 = -1;
#pragma unroll
    for (int e = 0; e < 8; ++e) { if (e == i0) continue; if (i1 < 0 || p[e] > p[i1]) i1 = e; }
    const float rs = 1.0f / (p[i0] + p[i1]);
    if (lane < 8)
        combine[t * 8 + lane] = (lane == i0) ? p[i0] * rs : (lane == i1) ? p[i1] * rs : 0.0f;
}

// ---------------- phase 2: H = gelu(X @ Wall^T + bias) * scale ----------------
// M=8192, N=4608, K=2048.  A = X (f32, cvt in reg), B = Wall bf16 [4608,2048] (async).
__global__ __launch_bounds__(256) void down_kernel(const float* __restrict__ X,
                                                   const bf16_t* __restrict__ Wall,
                                                   const float* __restrict__ Bd,
                                                   const float* __restrict__ Bsd,
                                                   const float* __restrict__ combine,
                                                   bf16_t* __restrict__ H) {
    __shared__ uint4 As4[128 * 8];   // [row][granule], granule XOR-swizzled by row&7
    __shared__ uint4 Bs4[128 * 8];
    const int tid = threadIdx.x;
    const int lane = tid & 63, wv = tid >> 6;
    const int wm = wv >> 1, wn = wv & 1;
    const int tile_m = blockIdx.y * 128, tile_n = blockIdx.x * 128;
    const int sr = tid >> 3;                       // staging row (0..31)
    const int sg = tid & 7;                        // staging granule
    const int sp = sg ^ (sr & 7);                  // swizzled LDS position
    const int gB = (lane & 7) ^ ((lane >> 3) & 7); // async src granule for lane

    f32x4 acc[4][4];
#pragma unroll
    for (int i = 0; i < 4; ++i)
#pragma unroll
        for (int j = 0; j < 4; ++j) acc[i][j] = (f32x4){0.f, 0.f, 0.f, 0.f};

    for (int kt = 0; kt < D_IN / 64; ++kt) {
        const int k0 = kt * 64;
        // B: async 16B, 4 chunks per wave (chunk = 8 rows x 1KB)
#pragma unroll
        for (int j = 0; j < 4; ++j) {
            const int c = wv * 4 + j;
            const int rr = c * 8 + (lane >> 3);
            async16(Wall + (size_t)(tile_n + rr) * D_IN + k0 + gB * 8, &Bs4[c * 64]);
        }
        // A: f32 load + cvt, swizzled ds_write
#pragma unroll
        for (int i = 0; i < 4; ++i) {
            const int r = i * 32 + sr;
            As4[r * 8 + sp] = ld_cvt8(X + (size_t)(tile_m + r) * D_IN + k0 + sg * 8);
        }
        __syncthreads();
#pragma unroll
        for (int ks = 0; ks < 2; ++ks) {
            bf16x8 af[4], bfr[4];
#pragma unroll
            for (int i = 0; i < 4; ++i) {
                const int ar = wm * 64 + i * 16 + (lane & 15);
                af[i] = as_bf16x8(As4[ar * 8 + ((ks * 4 + (lane >> 4)) ^ (lane & 7))]);
                const int br = wn * 64 + i * 16 + (lane & 15);
                bfr[i] = as_bf16x8(Bs4[br * 8 + ((ks * 4 + (lane >> 4)) ^ (lane & 7))]);
            }
#pragma unroll
            for (int mi = 0; mi < 4; ++mi)
#pragma unroll
                for (int nj = 0; nj < 4; ++nj)
                    acc[mi][nj] = __builtin_amdgcn_mfma_f32_16x16x32_bf16(
                        af[mi], bfr[nj], acc[mi][nj], 0, 0, 0);
        }
        __syncthreads();
    }

#pragma unroll
    for (int nj = 0; nj < 4; ++nj) {
        const int n = tile_n + wn * 64 + nj * 16 + (lane & 15);
        const int slot = n >> 9;
        const float bias = (n < 4096 ? Bd[n] : Bsd[n - 4096]);
#pragma unroll
        for (int mi = 0; mi < 4; ++mi) {
            const int m0 = tile_m + wm * 64 + mi * 16 + ((lane >> 4) << 2);
#pragma unroll
            for (int r = 0; r < 4; ++r) {
                const int t = m0 + r;
                float v = gelu_f(acc[mi][nj][r] + bias);
                const float sc = (slot < 8) ? combine[t * 8 + slot] : 1.0f;
                H[(size_t)t * N2 + n] = (bf16_t)(v * sc);
            }
        }
    }
}

// ---------------- phase 3: Out = H @ WuAll^T + combine@bu + bs_u ----------------
// M=8192, N=2048, K=4608.  A = H bf16 (async), B = Wuall bf16 [9][2048][512] (async).
__global__ __launch_bounds__(256) void up_kernel(const bf16_t* __restrict__ H,
                                                 const bf16_t* __restrict__ Wuall,
                                                 const float* __restrict__ Bu,
                                                 const float* __restrict__ Bsu,
                                                 const float* __restrict__ combine,
                                                 float* __restrict__ Out) {
    __shared__ uint4 As4[128 * 8];
    __shared__ uint4 Bs4[128 * 8];
    const int tid = threadIdx.x;
    const int lane = tid & 63, wv = tid >> 6;
    const int wm = wv >> 1, wn = wv & 1;
    const int tile_m = blockIdx.y * 128, tile_n = blockIdx.x * 128;
    const int gB = (lane & 7) ^ ((lane >> 3) & 7);

    f32x4 acc[4][4];
#pragma unroll
    for (int i = 0; i < 4; ++i)
#pragma unroll
        for (int j = 0; j < 4; ++j) acc[i][j] = (f32x4){0.f, 0.f, 0.f, 0.f};

    for (int kt = 0; kt < K3 / 64; ++kt) {
        const int k0 = kt * 64;
        const int slot = k0 >> 9;
        const int b0 = k0 & 511;
        const bf16_t* wbase = Wuall + (size_t)slot * (D_IN * D_BOT);
#pragma unroll
        for (int j = 0; j < 4; ++j) {
            const int c = wv * 4 + j;
            const int rr = c * 8 + (lane >> 3);
            async16(H + (size_t)(tile_m + rr) * K3 + k0 + gB * 8, &As4[c * 64]);
            async16(wbase + (size_t)(tile_n + rr) * D_BOT + b0 + gB * 8, &Bs4[c * 64]);
        }
        __syncthreads();
#pragma unroll
        for (int ks = 0; ks < 2; ++ks) {
            bf16x8 af[4], bfr[4];
#pragma unroll
            for (int i = 0; i < 4; ++i) {
                const int ar = wm * 64 + i * 16 + (lane & 15);
                af[i] = as_bf16x8(As4[ar * 8 + ((ks * 4 + (lane >> 4)) ^ (lane & 7))]);
                const int br = wn * 64 + i * 16 + (lane & 15);
                bfr[i] = as_bf16x8(Bs4[br * 8 + ((ks * 4 + (lane >> 4)) ^ (lane & 7))]);
            }
#pragma unroll
            for (int mi = 0; mi < 4; ++mi)
#pragma unroll
                for (int nj = 0; nj < 4; ++nj)
                    acc[mi][nj] = __builtin_amdgcn_mfma_f32_16x16x32_bf16(
                        af[mi], bfr[nj], acc[mi][nj], 0, 0, 0);
        }
        __syncthreads();
    }

#pragma unroll
    for (int nj = 0; nj < 4; ++nj) {
        const int d = tile_n + wn * 64 + nj * 16 + (lane & 15);
        float buv[8];
#pragma unroll
        for (int e = 0; e < 8; ++e) buv[e] = Bu[e * D_IN + d];
        const float bsu = Bsu[d];
#pragma unroll
        for (int mi = 0; mi < 4; ++mi) {
            const int m0 = tile_m + wm * 64 + mi * 16 + ((lane >> 4) << 2);
#pragma unroll
            for (int r = 0; r < 4; ++r) {
                const int t = m0 + r;
                float v = acc[mi][nj][r] + bsu;
                const float* cr = combine + t * 8;
#pragma unroll
                for (int e = 0; e < 8; ++e) v += cr[e] * buv[e];
                Out[(size_t)t * D_IN + d] = v;
            }
        }
    }
}

// ---------------- launch ----------------
extern "C" void kernel_launch(void* const* d_in, const int* in_sizes, int n_in,
                              void* d_out, int out_size, void* d_ws, size_t ws_size,
                              hipStream_t stream) {
    const float* x   = (const float*)d_in[0];
    const float* gw  = (const float*)d_in[1];
    const float* wd  = (const float*)d_in[2];
    const float* bd  = (const float*)d_in[3];
    const float* wu  = (const float*)d_in[4];
    const float* bu  = (const float*)d_in[5];
    const float* wsd = (const float*)d_in[6];
    const float* bsd = (const float*)d_in[7];
    const float* wsu = (const float*)d_in[8];
    const float* bsu = (const float*)d_in[9];
    float* out = (float*)d_out;

    // workspace layout (total ~90.3 MB):
    //   combine  @ 0            : 8192*8*4      = 262,144
    //   H        @ 262,144      : 8192*4608*2   = 75,497,472
    //   Wall     @ 75,759,616   : 4608*2048*2   = 18,874,368  (down weights; reused for up)
    float* combine = (float*)d_ws;
    bf16_t* H     = (bf16_t*)((char*)d_ws + 262144);
    bf16_t* Wall  = (bf16_t*)((char*)d_ws + 75759616ull);

    // gate (f32, full precision routing)
    gate_kernel<<<T_TOK / 4, 256, 0, stream>>>(x, gw, combine);

    // convert down weights -> bf16 [4608, 2048] = [wd ; ws_d]
    cvt_kernel<<<(4096 * D_IN / 8) / 256, 256, 0, stream>>>(wd, Wall, 4096 * D_IN / 8);
    cvt_kernel<<<(512 * D_IN / 8) / 256, 256, 0, stream>>>(wsd, Wall + (size_t)4096 * D_IN, 512 * D_IN / 8);

    down_kernel<<<dim3(N2 / 128, T_TOK / 128), 256, 0, stream>>>(x, Wall, bd, bsd, combine, H);

    // convert up weights -> bf16 [9][2048][512] = [wu ; ws_u]  (overlays Wall region)
    cvt_kernel<<<(8 * D_IN * D_BOT / 8) / 256, 256, 0, stream>>>(wu, Wall, 8 * D_IN * D_BOT / 8);
    cvt_kernel<<<(D_IN * D_BOT / 8) / 256, 256, 0, stream>>>(wsu, Wall + (size_t)8 * D_IN * D_BOT, D_IN * D_BOT / 8);

    up_kernel<<<dim3(D_IN / 128, T_TOK / 128), 256, 0, stream>>>(H, Wall, bu, bsu, combine, out);
}

// Round 4
// 834.975 us; speedup vs baseline: 1.1918x; 1.0067x over previous
//
#include <hip/hip_runtime.h>
#include <hip/hip_bf16.h>

// ---------------- types / constants ----------------
typedef __bf16 bf16_t;
typedef __bf16 bf16x8 __attribute__((ext_vector_type(8)));
typedef float f32x4 __attribute__((ext_vector_type(4)));

#define T_TOK 8192
#define D_IN  2048
#define D_BOT 512
#define CAP   8192   // per-expert list capacity (worst case)

union U4B8 { uint4 u; bf16x8 b; };
__device__ __forceinline__ bf16x8 as_bf16x8(uint4 u) { U4B8 x; x.u = u; return x.b; }
__device__ __forceinline__ uint4 as_uint4(bf16x8 b) { U4B8 x; x.b = b; return x.u; }

typedef const __attribute__((address_space(1))) void gas_void;
typedef __attribute__((address_space(3))) void las_void;
__device__ __forceinline__ void async16(const void* g, void* l) {
    __builtin_amdgcn_global_load_lds((gas_void*)g, (las_void*)l, 16, 0, 0);
}

__device__ __forceinline__ uint4 ld_cvt8(const float* __restrict__ p) {
    f32x4 a0 = ((const f32x4*)p)[0];
    f32x4 a1 = ((const f32x4*)p)[1];
    bf16x8 v;
    v[0] = (bf16_t)a0[0]; v[1] = (bf16_t)a0[1]; v[2] = (bf16_t)a0[2]; v[3] = (bf16_t)a0[3];
    v[4] = (bf16_t)a1[0]; v[5] = (bf16_t)a1[1]; v[6] = (bf16_t)a1[2]; v[7] = (bf16_t)a1[3];
    return as_uint4(v);
}

__device__ __forceinline__ float gelu_f(float v) {
    return 0.5f * v * (1.0f + erff(v * 0.7071067811865476f));
}

// ---------------- tiny helpers ----------------
__global__ void zero_kernel(int* p) { if (threadIdx.x < 64) p[threadIdx.x] = 0; }

__global__ void prefix_kernel(const int* cnt, int* base) {
    if (threadIdx.x == 0) {
        int s = 0;
        for (int e = 0; e < 8; ++e) { base[e] = s; s += cnt[e]; }
        base[8] = s;
    }
}

__global__ __launch_bounds__(256) void cvt_kernel(const float* __restrict__ src,
                                                  bf16_t* __restrict__ dst, int n8) {
    const int i = blockIdx.x * 256 + threadIdx.x;
    if (i < n8) ((uint4*)dst)[i] = ld_cvt8(src + (size_t)i * 8);
}

// ---------------- gate + routing + list build (f32 routing math) ----------------
__global__ __launch_bounds__(256) void gate_kernel(const float* __restrict__ x,
                                                   const float* __restrict__ gw,
                                                   float* __restrict__ combine,
                                                   int* __restrict__ cnt,
                                                   int* __restrict__ cntr,
                                                   int* __restrict__ tokE,
                                                   int* __restrict__ tokR,
                                                   int* __restrict__ posR) {
    const int wave = threadIdx.x >> 6, lane = threadIdx.x & 63;
    const int t = blockIdx.x * 4 + wave;
    const float* xrow = x + (size_t)t * D_IN;
    float xr[32];
#pragma unroll
    for (int i = 0; i < 32; ++i) xr[i] = xrow[lane + (i << 6)];
    float p[8];
#pragma unroll
    for (int e = 0; e < 8; ++e) {
        const float* gr = gw + e * D_IN;
        float s = 0.f;
#pragma unroll
        for (int i = 0; i < 32; ++i) s += xr[i] * gr[lane + (i << 6)];
#pragma unroll
        for (int off = 32; off > 0; off >>= 1) s += __shfl_xor(s, off, 64);
        p[e] = s;
    }
    float m = p[0];
#pragma unroll
    for (int e = 1; e < 8; ++e) m = fmaxf(m, p[e]);
    float sum = 0.f;
#pragma unroll
    for (int e = 0; e < 8; ++e) { p[e] = expf(p[e] - m); sum += p[e]; }
    const float inv = 1.0f / sum;
#pragma unroll
    for (int e = 0; e < 8; ++e) p[e] *= inv;
    int i0 = 0;
#pragma unroll
    for (int e = 1; e < 8; ++e) if (p[e] > p[i0]) i0 = e;
    int i1 = -1;
#pragma unroll
    for (int e = 0; e < 8; ++e) { if (e == i0) continue; if (i1 < 0 || p[e] > p[i1]) i1 = e; }
    const float rs = 1.0f / (p[i0] + p[i1]);
    if (lane < 8)
        combine[t * 8 + lane] = (lane == i0) ? p[i0] * rs : (lane == i1) ? p[i1] * rs : 0.0f;
    if (lane == 0) {
        int p0 = atomicAdd(&cnt[i0], 1);
        tokE[i0 * CAP + p0] = t;
        int q0 = atomicAdd(&cntr[i0], 1);               // rank 0 -> cntr[0..7]
        tokR[i0 * CAP + q0] = t;  posR[i0 * CAP + q0] = p0;
        int p1 = atomicAdd(&cnt[i1], 1);
        tokE[i1 * CAP + p1] = t;
        int q1 = atomicAdd(&cntr[8 + i1], 1);           // rank 1 -> cntr[8..15]
        tokR[(8 + i1) * CAP + q1] = t;  posR[(8 + i1) * CAP + q1] = p1;
    }
}

// ---------------- sparse down: H[hbase+i,:] = gelu(X[tok]@W_e^T + b) * scale ----------------
// grid (4, 64, 9): z=expert (8=shared/identity). A gathered from Xbf (async), B = Wall bf16.
__global__ __launch_bounds__(256) void down_kernel(const bf16_t* __restrict__ Xbf,
                                                   const bf16_t* __restrict__ Wall,
                                                   const float* __restrict__ Bd,
                                                   const float* __restrict__ Bsd,
                                                   const float* __restrict__ combine,
                                                   const int* __restrict__ cnt,
                                                   const int* __restrict__ base,
                                                   const int* __restrict__ tokE,
                                                   bf16_t* __restrict__ H) {
    __shared__ uint4 As4[128 * 8];
    __shared__ uint4 Bs4[128 * 8];
    const int e = blockIdx.z;
    const int count = (e < 8) ? cnt[e] : T_TOK;
    const int m0 = blockIdx.y * 128;
    if (m0 >= count) return;
    const int hbase = (e < 8) ? base[e] : 2 * T_TOK;
    const int tid = threadIdx.x, lane = tid & 63, wv = tid >> 6;
    const int wm = wv >> 1, wn = wv & 1;
    const int tile_n = blockIdx.x * 128;
    const int gB = (lane & 7) ^ ((lane >> 3) & 7);

    const bf16_t* aAddr[4];
    const bf16_t* bAddr[4];
#pragma unroll
    for (int j = 0; j < 4; ++j) {
        const int rr = (wv * 4 + j) * 8 + (lane >> 3);
        int gi = m0 + rr; if (gi > count - 1) gi = count - 1;
        const int t = (e < 8) ? tokE[e * CAP + gi] : gi;
        aAddr[j] = Xbf + (size_t)t * D_IN + gB * 8;
        bAddr[j] = Wall + (size_t)(e * 512 + tile_n + rr) * D_IN + gB * 8;
    }

    f32x4 acc[4][4];
#pragma unroll
    for (int i = 0; i < 4; ++i)
#pragma unroll
        for (int j = 0; j < 4; ++j) acc[i][j] = (f32x4){0.f, 0.f, 0.f, 0.f};

    for (int kt = 0; kt < D_IN / 64; ++kt) {
        const int k0 = kt * 64;
#pragma unroll
        for (int j = 0; j < 4; ++j) {
            const int c = wv * 4 + j;
            async16(aAddr[j] + k0, &As4[c * 64]);
            async16(bAddr[j] + k0, &Bs4[c * 64]);
        }
        __syncthreads();
#pragma unroll
        for (int ks = 0; ks < 2; ++ks) {
            bf16x8 af[4], bfr[4];
#pragma unroll
            for (int i = 0; i < 4; ++i) {
                const int ar = wm * 64 + i * 16 + (lane & 15);
                af[i] = as_bf16x8(As4[ar * 8 + ((ks * 4 + (lane >> 4)) ^ (lane & 7))]);
                const int br = wn * 64 + i * 16 + (lane & 15);
                bfr[i] = as_bf16x8(Bs4[br * 8 + ((ks * 4 + (lane >> 4)) ^ (lane & 7))]);
            }
#pragma unroll
            for (int mi = 0; mi < 4; ++mi)
#pragma unroll
                for (int nj = 0; nj < 4; ++nj)
                    acc[mi][nj] = __builtin_amdgcn_mfma_f32_16x16x32_bf16(
                        af[mi], bfr[nj], acc[mi][nj], 0, 0, 0);
        }
        __syncthreads();
    }

#pragma unroll
    for (int nj = 0; nj < 4; ++nj) {
        const int nn = tile_n + wn * 64 + nj * 16 + (lane & 15);   // 0..511
        const float bias = (e < 8) ? Bd[e * 512 + nn] : Bsd[nn];
#pragma unroll
        for (int mi = 0; mi < 4; ++mi) {
            const int g0 = m0 + wm * 64 + mi * 16 + ((lane >> 4) << 2);
#pragma unroll
            for (int r = 0; r < 4; ++r) {
                const int gi = g0 + r;
                if (gi >= count) continue;
                const int t = (e < 8) ? tokE[e * CAP + gi] : gi;
                float v = gelu_f(acc[mi][nj][r] + bias);
                const float sc = (e < 8) ? combine[t * 8 + e] : 1.0f;
                H[(size_t)(hbase + gi) * D_BOT + nn] = (bf16_t)(v * sc);
            }
        }
    }
}

// ---------------- sparse up ----------------
// MODE 0: shared — Out[t,d]  = acc + bs_u[d] + combine[t]@bu[:,d]   (grid 16,64,1)
// MODE 1/2: rank r=MODE-1 —  Out[t,d] += acc                        (grid 16,64,8)
template <int MODE>
__global__ __launch_bounds__(256) void up_kernel(const bf16_t* __restrict__ H,
                                                 const bf16_t* __restrict__ Wup,
                                                 const float* __restrict__ Bu,
                                                 const float* __restrict__ Bsu,
                                                 const float* __restrict__ combine,
                                                 const int* __restrict__ cntr,
                                                 const int* __restrict__ base,
                                                 const int* __restrict__ tokR,
                                                 const int* __restrict__ posR,
                                                 float* __restrict__ Out) {
    __shared__ uint4 As4[128 * 8];
    __shared__ uint4 Bs4[128 * 8];
    const int e  = (MODE == 0) ? 8 : blockIdx.z;
    const int li = (MODE == 0) ? 0 : (MODE - 1) * 8 + blockIdx.z;
    const int count = (MODE == 0) ? T_TOK : cntr[li];
    const int m0 = blockIdx.y * 128;
    if (m0 >= count) return;
    const int hb = (MODE == 0) ? 2 * T_TOK : base[blockIdx.z];
    const int tid = threadIdx.x, lane = tid & 63, wv = tid >> 6;
    const int wm = wv >> 1, wn = wv & 1;
    const int tile_n = blockIdx.x * 128;
    const int gB = (lane & 7) ^ ((lane >> 3) & 7);

    const bf16_t* aAddr[4];
    const bf16_t* bAddr[4];
#pragma unroll
    for (int j = 0; j < 4; ++j) {
        const int rr = (wv * 4 + j) * 8 + (lane >> 3);
        int gi = m0 + rr; if (gi > count - 1) gi = count - 1;
        const int hrow = (MODE == 0) ? (hb + gi) : (hb + posR[li * CAP + gi]);
        aAddr[j] = H + (size_t)hrow * D_BOT + gB * 8;
        bAddr[j] = Wup + (size_t)(e * D_IN + tile_n + rr) * D_BOT + gB * 8;
    }

    f32x4 acc[4][4];
#pragma unroll
    for (int i = 0; i < 4; ++i)
#pragma unroll
        for (int j = 0; j < 4; ++j) acc[i][j] = (f32x4){0.f, 0.f, 0.f, 0.f};

    for (int kt = 0; kt < D_BOT / 64; ++kt) {
        const int k0 = kt * 64;
#pragma unroll
        for (int j = 0; j < 4; ++j) {
            const int c = wv * 4 + j;
            async16(aAddr[j] + k0, &As4[c * 64]);
            async16(bAddr[j] + k0, &Bs4[c * 64]);
        }
        __syncthreads();
#pragma unroll
        for (int ks = 0; ks < 2; ++ks) {
            bf16x8 af[4], bfr[4];
#pragma unroll
            for (int i = 0; i < 4; ++i) {
                const int ar = wm * 64 + i * 16 + (lane & 15);
                af[i] = as_bf16x8(As4[ar * 8 + ((ks * 4 + (lane >> 4)) ^ (lane & 7))]);
                const int br = wn * 64 + i * 16 + (lane & 15);
                bfr[i] = as_bf16x8(Bs4[br * 8 + ((ks * 4 + (lane >> 4)) ^ (lane & 7))]);
            }
#pragma unroll
            for (int mi = 0; mi < 4; ++mi)
#pragma unroll
                for (int nj = 0; nj < 4; ++nj)
                    acc[mi][nj] = __builtin_amdgcn_mfma_f32_16x16x32_bf16(
                        af[mi], bfr[nj], acc[mi][nj], 0, 0, 0);
        }
        __syncthreads();
    }

#pragma unroll
    for (int nj = 0; nj < 4; ++nj) {
        const int d = tile_n + wn * 64 + nj * 16 + (lane & 15);    // 0..2047
        float buv[8]; float bsu = 0.f;
        if (MODE == 0) {
#pragma unroll
            for (int ee = 0; ee < 8; ++ee) buv[ee] = Bu[ee * D_IN + d];
            bsu = Bsu[d];
        }
#pragma unroll
        for (int mi = 0; mi < 4; ++mi) {
            const int g0 = m0 + wm * 64 + mi * 16 + ((lane >> 4) << 2);
#pragma unroll
            for (int r = 0; r < 4; ++r) {
                const int gi = g0 + r;
                if (gi >= count) continue;
                if (MODE == 0) {
                    const int t = gi;
                    float v = acc[mi][nj][r] + bsu;
                    const float* cr = combine + t * 8;
#pragma unroll
                    for (int ee = 0; ee < 8; ++ee) v += cr[ee] * buv[ee];
                    Out[(size_t)t * D_IN + d] = v;
                } else {
                    const int t = tokR[li * CAP + gi];
                    Out[(size_t)t * D_IN + d] += acc[mi][nj][r];
                }
            }
        }
    }
}

// ---------------- launch ----------------
extern "C" void kernel_launch(void* const* d_in, const int* in_sizes, int n_in,
                              void* d_out, int out_size, void* d_ws, size_t ws_size,
                              hipStream_t stream) {
    const float* x   = (const float*)d_in[0];
    const float* gw  = (const float*)d_in[1];
    const float* wd  = (const float*)d_in[2];
    const float* bd  = (const float*)d_in[3];
    const float* wu  = (const float*)d_in[4];
    const float* bu  = (const float*)d_in[5];
    const float* wsd = (const float*)d_in[6];
    const float* bsd = (const float*)d_in[7];
    const float* wsu = (const float*)d_in[8];
    const float* bsu = (const float*)d_in[9];
    float* out = (float*)d_out;

    // workspace layout (~79.2 MB):
    char* ws = (char*)d_ws;
    float* combine = (float*)(ws + 0);                 // 262,144
    int*   meta    = (int*)(ws + 262144);              // cnt@0, cntr@16, base@32 (ints)
    int*   cnt  = meta;
    int*   cntr = meta + 16;
    int*   base = meta + 32;
    int*   tokE = (int*)(ws + 263168);                 // 8*8192*4 = 262,144
    int*   tokR = (int*)(ws + 525312);                 // 16*8192*4 = 524,288
    int*   posR = (int*)(ws + 1049600);                // 524,288
    bf16_t* Xbf = (bf16_t*)(ws + 1573888);             // 8192*2048*2 = 33,554,432
    bf16_t* H   = (bf16_t*)(ws + 35128320ull);         // 24576*512*2 = 25,165,824
    bf16_t* Wall= (bf16_t*)(ws + 60294144ull);         // down: 4608*2048*2 = 18.9 MB; up overlay: 9.4 MB

    zero_kernel<<<1, 64, 0, stream>>>(meta);
    gate_kernel<<<T_TOK / 4, 256, 0, stream>>>(x, gw, combine, cnt, cntr, tokE, tokR, posR);
    prefix_kernel<<<1, 64, 0, stream>>>(cnt, base);

    cvt_kernel<<<(T_TOK * D_IN / 8) / 256, 256, 0, stream>>>(x, Xbf, T_TOK * D_IN / 8);
    cvt_kernel<<<(4096 * D_IN / 8) / 256, 256, 0, stream>>>(wd, Wall, 4096 * D_IN / 8);
    cvt_kernel<<<(512 * D_IN / 8) / 256, 256, 0, stream>>>(wsd, Wall + (size_t)4096 * D_IN, 512 * D_IN / 8);

    down_kernel<<<dim3(4, 64, 9), 256, 0, stream>>>(Xbf, Wall, bd, bsd, combine, cnt, base, tokE, H);

    // up weights overlay: [wu ; ws_u] -> bf16 [9*2048, 512]
    cvt_kernel<<<(8 * D_IN * D_BOT / 8) / 256, 256, 0, stream>>>(wu, Wall, 8 * D_IN * D_BOT / 8);
    cvt_kernel<<<(D_IN * D_BOT / 8) / 256, 256, 0, stream>>>(wsu, Wall + (size_t)8 * D_IN * D_BOT, D_IN * D_BOT / 8);

    up_kernel<0><<<dim3(16, 64, 1), 256, 0, stream>>>(H, Wall, bu, bsu, combine, cntr, base, tokR, posR, out);
    up_kernel<1><<<dim3(16, 64, 8), 256, 0, stream>>>(H, Wall, bu, bsu, combine, cntr, base, tokR, posR, out);
    up_kernel<2><<<dim3(16, 64, 8), 256, 0, stream>>>(H, Wall, bu, bsu, combine, cntr, base, tokR, posR, out);
}

// Round 5
// 673.619 us; speedup vs baseline: 1.4773x; 1.2395x over previous
//
#include <hip/hip_runtime.h>
#include <hip/hip_bf16.h>

// ---------------- types / constants ----------------
typedef __bf16 bf16_t;
typedef __bf16 bf16x8 __attribute__((ext_vector_type(8)));
typedef float f32x4 __attribute__((ext_vector_type(4)));

#define T_TOK 8192
#define D_IN  2048
#define D_BOT 512
#define CAP   8192   // per-expert list capacity (worst case)

union U4B8 { uint4 u; bf16x8 b; };
__device__ __forceinline__ bf16x8 as_bf16x8(uint4 u) { U4B8 x; x.u = u; return x.b; }
__device__ __forceinline__ uint4 as_uint4(bf16x8 b) { U4B8 x; x.b = b; return x.u; }

typedef const __attribute__((address_space(1))) void gas_void;
typedef __attribute__((address_space(3))) void las_void;
__device__ __forceinline__ void async16(const void* g, void* l) {
    __builtin_amdgcn_global_load_lds((gas_void*)g, (las_void*)l, 16, 0, 0);
}

__device__ __forceinline__ uint4 ld_cvt8(const float* __restrict__ p) {
    f32x4 a0 = ((const f32x4*)p)[0];
    f32x4 a1 = ((const f32x4*)p)[1];
    bf16x8 v;
    v[0] = (bf16_t)a0[0]; v[1] = (bf16_t)a0[1]; v[2] = (bf16_t)a0[2]; v[3] = (bf16_t)a0[3];
    v[4] = (bf16_t)a1[0]; v[5] = (bf16_t)a1[1]; v[6] = (bf16_t)a1[2]; v[7] = (bf16_t)a1[3];
    return as_uint4(v);
}

__device__ __forceinline__ float gelu_f(float v) {
    return 0.5f * v * (1.0f + erff(v * 0.7071067811865476f));
}

__global__ __launch_bounds__(256) void cvt_kernel(const float* __restrict__ src,
                                                  bf16_t* __restrict__ dst, int n8) {
    const int i = blockIdx.x * 256 + threadIdx.x;
    if (i < n8) ((uint4*)dst)[i] = ld_cvt8(src + (size_t)i * 8);
}

// ---------------- gate: combine weights + packed selection (NO atomics) ----------------
__global__ __launch_bounds__(256) void gate_kernel(const float* __restrict__ x,
                                                   const float* __restrict__ gw,
                                                   float* __restrict__ combine,
                                                   int* __restrict__ sel) {
    const int wave = threadIdx.x >> 6, lane = threadIdx.x & 63;
    const int t = blockIdx.x * 4 + wave;
    const float* xrow = x + (size_t)t * D_IN;
    float xr[32];
#pragma unroll
    for (int i = 0; i < 32; ++i) xr[i] = xrow[lane + (i << 6)];
    float p[8];
#pragma unroll
    for (int e = 0; e < 8; ++e) {
        const float* gr = gw + e * D_IN;
        float s = 0.f;
#pragma unroll
        for (int i = 0; i < 32; ++i) s += xr[i] * gr[lane + (i << 6)];
#pragma unroll
        for (int off = 32; off > 0; off >>= 1) s += __shfl_xor(s, off, 64);
        p[e] = s;
    }
    float m = p[0];
#pragma unroll
    for (int e = 1; e < 8; ++e) m = fmaxf(m, p[e]);
    float sum = 0.f;
#pragma unroll
    for (int e = 0; e < 8; ++e) { p[e] = expf(p[e] - m); sum += p[e]; }
    const float inv = 1.0f / sum;
#pragma unroll
    for (int e = 0; e < 8; ++e) p[e] *= inv;
    int i0 = 0;
#pragma unroll
    for (int e = 1; e < 8; ++e) if (p[e] > p[i0]) i0 = e;
    int i1 = -1;
#pragma unroll
    for (int e = 0; e < 8; ++e) { if (e == i0) continue; if (i1 < 0 || p[e] > p[i1]) i1 = e; }
    const float rs = 1.0f / (p[i0] + p[i1]);
    if (lane < 8)
        combine[t * 8 + lane] = (lane == i0) ? p[i0] * rs : (lane == i1) ? p[i1] * rs : 0.0f;
    if (lane == 0) sel[t] = i0 | (i1 << 4);
}

// ---------------- deterministic list build: single block, counting sort ----------------
// meta: cnt = meta[0..7], cntr = meta[16..31] (li = r*8+e), base = meta[32..40]
__global__ __launch_bounds__(1024) void build_kernel(const int* __restrict__ sel,
                                                     int* __restrict__ meta,
                                                     int* __restrict__ tokE,
                                                     int* __restrict__ tokR,
                                                     int* __restrict__ posR) {
    __shared__ unsigned short cAll[8][1024];
    __shared__ unsigned short cR0[8][1024];
    __shared__ unsigned short cR1[8][1024];
    const int tid = threadIdx.x;
#pragma unroll
    for (int e = 0; e < 8; ++e) { cAll[e][tid] = 0; cR0[e][tid] = 0; cR1[e][tid] = 0; }
    __syncthreads();
    int sl[8];
#pragma unroll
    for (int j = 0; j < 8; ++j) sl[j] = sel[tid * 8 + j];
#pragma unroll
    for (int j = 0; j < 8; ++j) {
        const int e0 = sl[j] & 15, e1 = sl[j] >> 4;
        cAll[e0][tid]++; cAll[e1][tid]++; cR0[e0][tid]++; cR1[e1][tid]++;
    }
    __syncthreads();
    if (tid < 24) {
        unsigned short* arr = (tid < 8) ? cAll[tid] : (tid < 16) ? cR0[tid - 8] : cR1[tid - 16];
        int run = 0;
        for (int i = 0; i < 1024; ++i) { int v = arr[i]; arr[i] = (unsigned short)run; run += v; }
        if (tid < 8)       meta[tid] = run;            // cnt[e]
        else if (tid < 16) meta[16 + (tid - 8)] = run; // cntr[rank0]
        else               meta[24 + (tid - 16)] = run;// cntr[rank1]
    }
    __syncthreads();
    if (tid == 0) {
        int s = 0;
        for (int e = 0; e < 8; ++e) { meta[32 + e] = s; s += meta[e]; }
        meta[40] = s;
    }
#pragma unroll
    for (int j = 0; j < 8; ++j) {
        const int t = tid * 8 + j, e0 = sl[j] & 15, e1 = sl[j] >> 4;
        const int p0 = cAll[e0][tid]++;  tokE[e0 * CAP + p0] = t;
        const int q0 = cR0[e0][tid]++;   tokR[e0 * CAP + q0] = t;        posR[e0 * CAP + q0] = p0;
        const int p1 = cAll[e1][tid]++;  tokE[e1 * CAP + p1] = t;
        const int q1 = cR1[e1][tid]++;   tokR[(8 + e1) * CAP + q1] = t;  posR[(8 + e1) * CAP + q1] = p1;
    }
}

// ---------------- sparse down: H[hbase+i,:] = gelu(X[tok]@W_e^T + b) * scale ----------------
__global__ __launch_bounds__(256) void down_kernel(const bf16_t* __restrict__ Xbf,
                                                   const bf16_t* __restrict__ Wall,
                                                   const float* __restrict__ Bd,
                                                   const float* __restrict__ Bsd,
                                                   const float* __restrict__ combine,
                                                   const int* __restrict__ cnt,
                                                   const int* __restrict__ base,
                                                   const int* __restrict__ tokE,
                                                   bf16_t* __restrict__ H) {
    __shared__ uint4 As4[128 * 8];
    __shared__ uint4 Bs4[128 * 8];
    const int e = blockIdx.z;
    const int count = (e < 8) ? cnt[e] : T_TOK;
    const int m0 = blockIdx.y * 128;
    if (m0 >= count) return;
    const int hbase = (e < 8) ? base[e] : 2 * T_TOK;
    const int tid = threadIdx.x, lane = tid & 63, wv = tid >> 6;
    const int wm = wv >> 1, wn = wv & 1;
    const int tile_n = blockIdx.x * 128;
    const int gB = (lane & 7) ^ ((lane >> 3) & 7);

    const bf16_t* aAddr[4];
    const bf16_t* bAddr[4];
#pragma unroll
    for (int j = 0; j < 4; ++j) {
        const int rr = (wv * 4 + j) * 8 + (lane >> 3);
        int gi = m0 + rr; if (gi > count - 1) gi = count - 1;
        const int t = (e < 8) ? tokE[e * CAP + gi] : gi;
        aAddr[j] = Xbf + (size_t)t * D_IN + gB * 8;
        bAddr[j] = Wall + (size_t)(e * 512 + tile_n + rr) * D_IN + gB * 8;
    }

    f32x4 acc[4][4];
#pragma unroll
    for (int i = 0; i < 4; ++i)
#pragma unroll
        for (int j = 0; j < 4; ++j) acc[i][j] = (f32x4){0.f, 0.f, 0.f, 0.f};

    for (int kt = 0; kt < D_IN / 64; ++kt) {
        const int k0 = kt * 64;
#pragma unroll
        for (int j = 0; j < 4; ++j) {
            const int c = wv * 4 + j;
            async16(aAddr[j] + k0, &As4[c * 64]);
            async16(bAddr[j] + k0, &Bs4[c * 64]);
        }
        __syncthreads();
#pragma unroll
        for (int ks = 0; ks < 2; ++ks) {
            bf16x8 af[4], bfr[4];
#pragma unroll
            for (int i = 0; i < 4; ++i) {
                const int ar = wm * 64 + i * 16 + (lane & 15);
                af[i] = as_bf16x8(As4[ar * 8 + ((ks * 4 + (lane >> 4)) ^ (lane & 7))]);
                const int br = wn * 64 + i * 16 + (lane & 15);
                bfr[i] = as_bf16x8(Bs4[br * 8 + ((ks * 4 + (lane >> 4)) ^ (lane & 7))]);
            }
#pragma unroll
            for (int mi = 0; mi < 4; ++mi)
#pragma unroll
                for (int nj = 0; nj < 4; ++nj)
                    acc[mi][nj] = __builtin_amdgcn_mfma_f32_16x16x32_bf16(
                        af[mi], bfr[nj], acc[mi][nj], 0, 0, 0);
        }
        __syncthreads();
    }

#pragma unroll
    for (int nj = 0; nj < 4; ++nj) {
        const int nn = tile_n + wn * 64 + nj * 16 + (lane & 15);   // 0..511
        const float bias = (e < 8) ? Bd[e * 512 + nn] : Bsd[nn];
#pragma unroll
        for (int mi = 0; mi < 4; ++mi) {
            const int g0 = m0 + wm * 64 + mi * 16 + ((lane >> 4) << 2);
#pragma unroll
            for (int r = 0; r < 4; ++r) {
                const int gi = g0 + r;
                if (gi >= count) continue;
                const int t = (e < 8) ? tokE[e * CAP + gi] : gi;
                float v = gelu_f(acc[mi][nj][r] + bias);
                const float sc = (e < 8) ? combine[t * 8 + e] : 1.0f;
                H[(size_t)(hbase + gi) * D_BOT + nn] = (bf16_t)(v * sc);
            }
        }
    }
}

// ---------------- sparse up ----------------
// MODE 0: shared — Out[t,d]  = acc + bs_u[d] + combine[t]@bu[:,d]   (grid 16,64,1)
// MODE 1/2: rank r=MODE-1 —  Out[t,d] += acc                        (grid 16,64,8)
template <int MODE>
__global__ __launch_bounds__(256) void up_kernel(const bf16_t* __restrict__ H,
                                                 const bf16_t* __restrict__ Wup,
                                                 const float* __restrict__ Bu,
                                                 const float* __restrict__ Bsu,
                                                 const float* __restrict__ combine,
                                                 const int* __restrict__ cntr,
                                                 const int* __restrict__ base,
                                                 const int* __restrict__ tokR,
                                                 const int* __restrict__ posR,
                                                 float* __restrict__ Out) {
    __shared__ uint4 As4[128 * 8];
    __shared__ uint4 Bs4[128 * 8];
    const int e  = (MODE == 0) ? 8 : blockIdx.z;
    const int li = (MODE == 0) ? 0 : (MODE - 1) * 8 + blockIdx.z;
    const int count = (MODE == 0) ? T_TOK : cntr[li];
    const int m0 = blockIdx.y * 128;
    if (m0 >= count) return;
    const int hb = (MODE == 0) ? 2 * T_TOK : base[blockIdx.z];
    const int tid = threadIdx.x, lane = tid & 63, wv = tid >> 6;
    const int wm = wv >> 1, wn = wv & 1;
    const int tile_n = blockIdx.x * 128;
    const int gB = (lane & 7) ^ ((lane >> 3) & 7);

    const bf16_t* aAddr[4];
    const bf16_t* bAddr[4];
#pragma unroll
    for (int j = 0; j < 4; ++j) {
        const int rr = (wv * 4 + j) * 8 + (lane >> 3);
        int gi = m0 + rr; if (gi > count - 1) gi = count - 1;
        const int hrow = (MODE == 0) ? (hb + gi) : (hb + posR[li * CAP + gi]);
        aAddr[j] = H + (size_t)hrow * D_BOT + gB * 8;
        bAddr[j] = Wup + (size_t)(e * D_IN + tile_n + rr) * D_BOT + gB * 8;
    }

    f32x4 acc[4][4];
#pragma unroll
    for (int i = 0; i < 4; ++i)
#pragma unroll
        for (int j = 0; j < 4; ++j) acc[i][j] = (f32x4){0.f, 0.f, 0.f, 0.f};

    for (int kt = 0; kt < D_BOT / 64; ++kt) {
        const int k0 = kt * 64;
#pragma unroll
        for (int j = 0; j < 4; ++j) {
            const int c = wv * 4 + j;
            async16(aAddr[j] + k0, &As4[c * 64]);
            async16(bAddr[j] + k0, &Bs4[c * 64]);
        }
        __syncthreads();
#pragma unroll
        for (int ks = 0; ks < 2; ++ks) {
            bf16x8 af[4], bfr[4];
#pragma unroll
            for (int i = 0; i < 4; ++i) {
                const int ar = wm * 64 + i * 16 + (lane & 15);
                af[i] = as_bf16x8(As4[ar * 8 + ((ks * 4 + (lane >> 4)) ^ (lane & 7))]);
                const int br = wn * 64 + i * 16 + (lane & 15);
                bfr[i] = as_bf16x8(Bs4[br * 8 + ((ks * 4 + (lane >> 4)) ^ (lane & 7))]);
            }
#pragma unroll
            for (int mi = 0; mi < 4; ++mi)
#pragma unroll
                for (int nj = 0; nj < 4; ++nj)
                    acc[mi][nj] = __builtin_amdgcn_mfma_f32_16x16x32_bf16(
                        af[mi], bfr[nj], acc[mi][nj], 0, 0, 0);
        }
        __syncthreads();
    }

#pragma unroll
    for (int nj = 0; nj < 4; ++nj) {
        const int d = tile_n + wn * 64 + nj * 16 + (lane & 15);    // 0..2047
        float buv[8]; float bsu = 0.f;
        if (MODE == 0) {
#pragma unroll
            for (int ee = 0; ee < 8; ++ee) buv[ee] = Bu[ee * D_IN + d];
            bsu = Bsu[d];
        }
#pragma unroll
        for (int mi = 0; mi < 4; ++mi) {
            const int g0 = m0 + wm * 64 + mi * 16 + ((lane >> 4) << 2);
#pragma unroll
            for (int r = 0; r < 4; ++r) {
                const int gi = g0 + r;
                if (gi >= count) continue;
                if (MODE == 0) {
                    const int t = gi;
                    float v = acc[mi][nj][r] + bsu;
                    const float* cr = combine + t * 8;
#pragma unroll
                    for (int ee = 0; ee < 8; ++ee) v += cr[ee] * buv[ee];
                    Out[(size_t)t * D_IN + d] = v;
                } else {
                    const int t = tokR[li * CAP + gi];
                    Out[(size_t)t * D_IN + d] += acc[mi][nj][r];
                }
            }
        }
    }
}

// ---------------- launch ----------------
extern "C" void kernel_launch(void* const* d_in, const int* in_sizes, int n_in,
                              void* d_out, int out_size, void* d_ws, size_t ws_size,
                              hipStream_t stream) {
    const float* x   = (const float*)d_in[0];
    const float* gw  = (const float*)d_in[1];
    const float* wd  = (const float*)d_in[2];
    const float* bd  = (const float*)d_in[3];
    const float* wu  = (const float*)d_in[4];
    const float* bu  = (const float*)d_in[5];
    const float* wsd = (const float*)d_in[6];
    const float* bsd = (const float*)d_in[7];
    const float* wsu = (const float*)d_in[8];
    const float* bsu = (const float*)d_in[9];
    float* out = (float*)d_out;

    // workspace layout (~79.2 MB):
    char* ws = (char*)d_ws;
    float* combine = (float*)(ws + 0);                 // 262,144
    int*   meta    = (int*)(ws + 262144);              // cnt@0, cntr@16, base@32
    int*   cnt  = meta;
    int*   cntr = meta + 16;
    int*   base = meta + 32;
    int*   tokE = (int*)(ws + 263168);                 // 262,144
    int*   tokR = (int*)(ws + 525312);                 // 524,288
    int*   posR = (int*)(ws + 1049600);                // 524,288
    int*   sel  = (int*)(ws + 1573888);                // 32,768
    bf16_t* Xbf = (bf16_t*)(ws + 1606656);             // 33,554,432
    bf16_t* H   = (bf16_t*)(ws + 35161088ull);         // 25,165,824
    bf16_t* Wall= (bf16_t*)(ws + 60326912ull);         // 18,874,368

    gate_kernel<<<T_TOK / 4, 256, 0, stream>>>(x, gw, combine, sel);
    build_kernel<<<1, 1024, 0, stream>>>(sel, meta, tokE, tokR, posR);

    cvt_kernel<<<(T_TOK * D_IN / 8) / 256, 256, 0, stream>>>(x, Xbf, T_TOK * D_IN / 8);
    cvt_kernel<<<(4096 * D_IN / 8) / 256, 256, 0, stream>>>(wd, Wall, 4096 * D_IN / 8);
    cvt_kernel<<<(512 * D_IN / 8) / 256, 256, 0, stream>>>(wsd, Wall + (size_t)4096 * D_IN, 512 * D_IN / 8);

    down_kernel<<<dim3(4, 64, 9), 256, 0, stream>>>(Xbf, Wall, bd, bsd, combine, cnt, base, tokE, H);

    cvt_kernel<<<(8 * D_IN * D_BOT / 8) / 256, 256, 0, stream>>>(wu, Wall, 8 * D_IN * D_BOT / 8);
    cvt_kernel<<<(D_IN * D_BOT / 8) / 256, 256, 0, stream>>>(wsu, Wall + (size_t)8 * D_IN * D_BOT, D_IN * D_BOT / 8);

    up_kernel<0><<<dim3(16, 64, 1), 256, 0, stream>>>(H, Wall, bu, bsu, combine, cntr, base, tokR, posR, out);
    up_kernel<1><<<dim3(16, 64, 8), 256, 0, stream>>>(H, Wall, bu, bsu, combine, cntr, base, tokR, posR, out);
    up_kernel<2><<<dim3(16, 64, 8), 256, 0, stream>>>(H, Wall, bu, bsu, combine, cntr, base, tokR, posR, out);
}

// Round 6
// 589.330 us; speedup vs baseline: 1.6885x; 1.1430x over previous
//
#include <hip/hip_runtime.h>
#include <hip/hip_bf16.h>

// ---------------- types / constants ----------------
typedef __bf16 bf16_t;
typedef __bf16 bf16x8 __attribute__((ext_vector_type(8)));
typedef float f32x4 __attribute__((ext_vector_type(4)));

#define T_TOK 8192
#define D_IN  2048
#define D_BOT 512
#define CAP   8192
#define SH_BASE 17408          // shared slot rows start here (>= max padded expert rows 17400)
#define NROWS_H 25600          // SH_BASE + 8192

union U4B8 { uint4 u; bf16x8 b; };
__device__ __forceinline__ bf16x8 as_bf16x8(uint4 u) { U4B8 x; x.u = u; return x.b; }
__device__ __forceinline__ uint4 as_uint4(bf16x8 b) { U4B8 x; x.b = b; return x.u; }

typedef const __attribute__((address_space(1))) void gas_void;
typedef __attribute__((address_space(3))) void las_void;
__device__ __forceinline__ void async16(const void* g, void* l) {
    __builtin_amdgcn_global_load_lds((gas_void*)g, (las_void*)l, 16, 0, 0);
}

__device__ __forceinline__ uint4 ld_cvt8(const float* __restrict__ p) {
    f32x4 a0 = ((const f32x4*)p)[0];
    f32x4 a1 = ((const f32x4*)p)[1];
    bf16x8 v;
    v[0] = (bf16_t)a0[0]; v[1] = (bf16_t)a0[1]; v[2] = (bf16_t)a0[2]; v[3] = (bf16_t)a0[3];
    v[4] = (bf16_t)a1[0]; v[5] = (bf16_t)a1[1]; v[6] = (bf16_t)a1[2]; v[7] = (bf16_t)a1[3];
    return as_uint4(v);
}

__device__ __forceinline__ float gelu_f(float v) {
    return 0.5f * v * (1.0f + erff(v * 0.7071067811865476f));
}

__global__ __launch_bounds__(256) void cvt_kernel(const float* __restrict__ src,
                                                  bf16_t* __restrict__ dst, int n8) {
    const int i = blockIdx.x * 256 + threadIdx.x;
    if (i < n8) ((uint4*)dst)[i] = ld_cvt8(src + (size_t)i * 8);
}

// ---------------- gate: combine + sel + Xbf (fused x-convert; NO atomics) ----------------
__global__ __launch_bounds__(256) void gate_kernel(const float* __restrict__ x,
                                                   const float* __restrict__ gw,
                                                   float* __restrict__ combine,
                                                   int* __restrict__ sel,
                                                   bf16_t* __restrict__ Xbf) {
    const int wave = threadIdx.x >> 6, lane = threadIdx.x & 63;
    const int t = blockIdx.x * 4 + wave;
    const float* xrow = x + (size_t)t * D_IN;
    // chunked: chunk c covers [c*512 + lane*8, +8)
    f32x4 xa[4][2];
#pragma unroll
    for (int c = 0; c < 4; ++c) {
        const float* p = xrow + c * 512 + lane * 8;
        xa[c][0] = ((const f32x4*)p)[0];
        xa[c][1] = ((const f32x4*)p)[1];
    }
    // write bf16 copy of x (coalesced uint4)
#pragma unroll
    for (int c = 0; c < 4; ++c) {
        bf16x8 v;
#pragma unroll
        for (int j = 0; j < 4; ++j) { v[j] = (bf16_t)xa[c][0][j]; v[4 + j] = (bf16_t)xa[c][1][j]; }
        *(uint4*)(Xbf + (size_t)t * D_IN + c * 512 + lane * 8) = as_uint4(v);
    }
    float p[8];
#pragma unroll
    for (int e = 0; e < 8; ++e) {
        const float* gr = gw + e * D_IN;
        float s = 0.f;
#pragma unroll
        for (int c = 0; c < 4; ++c) {
            const float* q = gr + c * 512 + lane * 8;
            f32x4 g0 = ((const f32x4*)q)[0], g1 = ((const f32x4*)q)[1];
#pragma unroll
            for (int j = 0; j < 4; ++j) s += xa[c][0][j] * g0[j] + xa[c][1][j] * g1[j];
        }
#pragma unroll
        for (int off = 32; off > 0; off >>= 1) s += __shfl_xor(s, off, 64);
        p[e] = s;
    }
    float m = p[0];
#pragma unroll
    for (int e = 1; e < 8; ++e) m = fmaxf(m, p[e]);
    float sum = 0.f;
#pragma unroll
    for (int e = 0; e < 8; ++e) { p[e] = expf(p[e] - m); sum += p[e]; }
    const float inv = 1.0f / sum;
#pragma unroll
    for (int e = 0; e < 8; ++e) p[e] *= inv;
    int i0 = 0;
#pragma unroll
    for (int e = 1; e < 8; ++e) if (p[e] > p[i0]) i0 = e;
    int i1 = -1;
#pragma unroll
    for (int e = 0; e < 8; ++e) { if (e == i0) continue; if (i1 < 0 || p[e] > p[i1]) i1 = e; }
    const float rs = 1.0f / (p[i0] + p[i1]);
    if (lane < 8)
        combine[t * 8 + lane] = (lane == i0) ? p[i0] * rs : (lane == i1) ? p[i1] * rs : 0.0f;
    if (lane == 0) sel[t] = i0 | (i1 << 4);
}

// ---------------- deterministic list build (counting sort) ----------------
// meta: cnt = meta[0..7], pbase = meta[8..16] (padded to 128-multiples)
__global__ __launch_bounds__(1024) void build_kernel(const int* __restrict__ sel,
                                                     int* __restrict__ meta,
                                                     int* __restrict__ tokE) {
    __shared__ unsigned short cAll[8][1024];
    const int tid = threadIdx.x;
#pragma unroll
    for (int e = 0; e < 8; ++e) cAll[e][tid] = 0;
    __syncthreads();
    int sl[8];
#pragma unroll
    for (int j = 0; j < 8; ++j) sl[j] = sel[tid * 8 + j];
#pragma unroll
    for (int j = 0; j < 8; ++j) { cAll[sl[j] & 15][tid]++; cAll[sl[j] >> 4][tid]++; }
    __syncthreads();
    if (tid < 8) {
        unsigned short* arr = cAll[tid];
        int run = 0;
        for (int i = 0; i < 1024; ++i) { int v = arr[i]; arr[i] = (unsigned short)run; run += v; }
        meta[tid] = run;
    }
    __syncthreads();
    if (tid == 0) {
        int s = 0;
        for (int e = 0; e < 8; ++e) {
            meta[8 + e] = s;
            s += ((meta[e] + 127) / 128) * 128;
        }
        meta[16] = s;   // padded end of expert region (<= 17400 < SH_BASE)
    }
#pragma unroll
    for (int j = 0; j < 8; ++j) {
        const int t = tid * 8 + j, e0 = sl[j] & 15, e1 = sl[j] >> 4;
        const int p0 = cAll[e0][tid]++;  tokE[e0 * CAP + p0] = t;
        const int p1 = cAll[e1][tid]++;  tokE[e1 * CAP + p1] = t;
    }
}

// ---------------- Out init: Out[t,d] = bs_u[d] + combine[t,:] @ bu[:,d] ----------------
__global__ __launch_bounds__(256) void initout_kernel(const float* __restrict__ bu,
                                                      const float* __restrict__ bsu,
                                                      const float* __restrict__ combine,
                                                      float* __restrict__ Out) {
    const int t = blockIdx.x;
    const int d = threadIdx.x * 8;
    float c[8];
#pragma unroll
    for (int e = 0; e < 8; ++e) c[e] = combine[t * 8 + e];
    f32x4 r0 = ((const f32x4*)(bsu + d))[0];
    f32x4 r1 = ((const f32x4*)(bsu + d))[1];
#pragma unroll
    for (int e = 0; e < 8; ++e) {
        const float* p = bu + e * D_IN + d;
        f32x4 b0 = ((const f32x4*)p)[0], b1 = ((const f32x4*)p)[1];
#pragma unroll
        for (int j = 0; j < 4; ++j) { r0[j] += c[e] * b0[j]; r1[j] += c[e] * b1[j]; }
    }
    ((f32x4*)(Out + (size_t)t * D_IN + d))[0] = r0;
    ((f32x4*)(Out + (size_t)t * D_IN + d))[1] = r1;
}

// ---------------- sparse down: H[pbase[e]+i,:] = gelu(X[tok]@W_e^T + b) * scale ----------------
__global__ __launch_bounds__(256) void down_kernel(const bf16_t* __restrict__ Xbf,
                                                   const bf16_t* __restrict__ Wall,
                                                   const float* __restrict__ Bd,
                                                   const float* __restrict__ Bsd,
                                                   const float* __restrict__ combine,
                                                   const int* __restrict__ meta,
                                                   const int* __restrict__ tokE,
                                                   bf16_t* __restrict__ H) {
    __shared__ uint4 As4[128 * 8];
    __shared__ uint4 Bs4[128 * 8];
    const int e = blockIdx.z;
    const int count = (e < 8) ? meta[e] : T_TOK;
    const int m0 = blockIdx.y * 128;
    if (m0 >= count) return;
    const int hbase = (e < 8) ? meta[8 + e] : SH_BASE;
    const int tid = threadIdx.x, lane = tid & 63, wv = tid >> 6;
    const int wm = wv >> 1, wn = wv & 1;
    const int tile_n = blockIdx.x * 128;
    const int gB = (lane & 7) ^ ((lane >> 3) & 7);

    const bf16_t* aAddr[4];
    const bf16_t* bAddr[4];
#pragma unroll
    for (int j = 0; j < 4; ++j) {
        const int rr = (wv * 4 + j) * 8 + (lane >> 3);
        int gi = m0 + rr; if (gi > count - 1) gi = count - 1;
        const int t = (e < 8) ? tokE[e * CAP + gi] : gi;
        aAddr[j] = Xbf + (size_t)t * D_IN + gB * 8;
        bAddr[j] = Wall + (size_t)(e * 512 + tile_n + rr) * D_IN + gB * 8;
    }

    f32x4 acc[4][4];
#pragma unroll
    for (int i = 0; i < 4; ++i)
#pragma unroll
        for (int j = 0; j < 4; ++j) acc[i][j] = (f32x4){0.f, 0.f, 0.f, 0.f};

    for (int kt = 0; kt < D_IN / 64; ++kt) {
        const int k0 = kt * 64;
#pragma unroll
        for (int j = 0; j < 4; ++j) {
            const int c = wv * 4 + j;
            async16(aAddr[j] + k0, &As4[c * 64]);
            async16(bAddr[j] + k0, &Bs4[c * 64]);
        }
        __syncthreads();
#pragma unroll
        for (int ks = 0; ks < 2; ++ks) {
            bf16x8 af[4], bfr[4];
#pragma unroll
            for (int i = 0; i < 4; ++i) {
                const int ar = wm * 64 + i * 16 + (lane & 15);
                af[i] = as_bf16x8(As4[ar * 8 + ((ks * 4 + (lane >> 4)) ^ (lane & 7))]);
                const int br = wn * 64 + i * 16 + (lane & 15);
                bfr[i] = as_bf16x8(Bs4[br * 8 + ((ks * 4 + (lane >> 4)) ^ (lane & 7))]);
            }
#pragma unroll
            for (int mi = 0; mi < 4; ++mi)
#pragma unroll
                for (int nj = 0; nj < 4; ++nj)
                    acc[mi][nj] = __builtin_amdgcn_mfma_f32_16x16x32_bf16(
                        af[mi], bfr[nj], acc[mi][nj], 0, 0, 0);
        }
        __syncthreads();
    }

#pragma unroll
    for (int nj = 0; nj < 4; ++nj) {
        const int nn = tile_n + wn * 64 + nj * 16 + (lane & 15);   // 0..511
        const float bias = (e < 8) ? Bd[e * 512 + nn] : Bsd[nn];
#pragma unroll
        for (int mi = 0; mi < 4; ++mi) {
            const int g0 = m0 + wm * 64 + mi * 16 + ((lane >> 4) << 2);
#pragma unroll
            for (int r = 0; r < 4; ++r) {
                const int gi = g0 + r;
                if (gi >= count) continue;
                const int t = (e < 8) ? tokE[e * CAP + gi] : gi;
                float v = gelu_f(acc[mi][nj][r] + bias);
                const float sc = (e < 8) ? combine[t * 8 + e] : 1.0f;
                H[(size_t)(hbase + gi) * D_BOT + nn] = (bf16_t)(v * sc);
            }
        }
    }
}

// ---------------- fused up: Out[t,:] += H[row,:] @ Wu_slot^T  (atomicAdd) ----------------
// rows 0..pbase[8]: expert region (padded, slot via pbase lookup); rows >= SH_BASE: shared.
__global__ __launch_bounds__(256) void up_kernel(const bf16_t* __restrict__ H,
                                                 const bf16_t* __restrict__ Wup,
                                                 const int* __restrict__ meta,
                                                 const int* __restrict__ tokE,
                                                 float* __restrict__ Out) {
    __shared__ uint4 As4[128 * 8];
    __shared__ uint4 Bs4[128 * 8];
    const int row0 = blockIdx.y * 128;
    int slot = 8, ebase = SH_BASE, ecnt = T_TOK;
    if (row0 < SH_BASE) {
        if (row0 >= meta[16]) return;      // hole between padded expert region and shared
#pragma unroll
        for (int e = 0; e < 8; ++e)
            if (row0 >= meta[8 + e]) slot = e;   // meta[8+e] nondecreasing -> last match
        if (slot == 8) return;             // unreachable guard
        ebase = meta[8 + slot];
        ecnt = meta[slot];
    }
    const int tid = threadIdx.x, lane = tid & 63, wv = tid >> 6;
    const int wm = wv >> 1, wn = wv & 1;
    const int tile_n = blockIdx.x * 128;
    const int gB = (lane & 7) ^ ((lane >> 3) & 7);

    const bf16_t* aAddr[4];
    const bf16_t* bAddr[4];
#pragma unroll
    for (int j = 0; j < 4; ++j) {
        const int rr = (wv * 4 + j) * 8 + (lane >> 3);
        aAddr[j] = H + (size_t)(row0 + rr) * D_BOT + gB * 8;            // sequential rows!
        bAddr[j] = Wup + (size_t)(slot * D_IN + tile_n + rr) * D_BOT + gB * 8;
    }

    f32x4 acc[4][4];
#pragma unroll
    for (int i = 0; i < 4; ++i)
#pragma unroll
        for (int j = 0; j < 4; ++j) acc[i][j] = (f32x4){0.f, 0.f, 0.f, 0.f};

    for (int kt = 0; kt < D_BOT / 64; ++kt) {
        const int k0 = kt * 64;
#pragma unroll
        for (int j = 0; j < 4; ++j) {
            const int c = wv * 4 + j;
            async16(aAddr[j] + k0, &As4[c * 64]);
            async16(bAddr[j] + k0, &Bs4[c * 64]);
        }
        __syncthreads();
#pragma unroll
        for (int ks = 0; ks < 2; ++ks) {
            bf16x8 af[4], bfr[4];
#pragma unroll
            for (int i = 0; i < 4; ++i) {
                const int ar = wm * 64 + i * 16 + (lane & 15);
                af[i] = as_bf16x8(As4[ar * 8 + ((ks * 4 + (lane >> 4)) ^ (lane & 7))]);
                const int br = wn * 64 + i * 16 + (lane & 15);
                bfr[i] = as_bf16x8(Bs4[br * 8 + ((ks * 4 + (lane >> 4)) ^ (lane & 7))]);
            }
#pragma unroll
            for (int mi = 0; mi < 4; ++mi)
#pragma unroll
                for (int nj = 0; nj < 4; ++nj)
                    acc[mi][nj] = __builtin_amdgcn_mfma_f32_16x16x32_bf16(
                        af[mi], bfr[nj], acc[mi][nj], 0, 0, 0);
        }
        __syncthreads();
    }

#pragma unroll
    for (int nj = 0; nj < 4; ++nj) {
        const int d = tile_n + wn * 64 + nj * 16 + (lane & 15);    // 0..2047
#pragma unroll
        for (int mi = 0; mi < 4; ++mi) {
            const int r0 = row0 + wm * 64 + mi * 16 + ((lane >> 4) << 2);
#pragma unroll
            for (int r = 0; r < 4; ++r) {
                const int gi = r0 + r - ebase;
                if (gi >= ecnt) continue;                 // padding rows
                const int t = (slot == 8) ? gi : tokE[slot * CAP + gi];
                atomicAdd(&Out[(size_t)t * D_IN + d], acc[mi][nj][r]);
            }
        }
    }
}

// ---------------- launch ----------------
extern "C" void kernel_launch(void* const* d_in, const int* in_sizes, int n_in,
                              void* d_out, int out_size, void* d_ws, size_t ws_size,
                              hipStream_t stream) {
    const float* x   = (const float*)d_in[0];
    const float* gw  = (const float*)d_in[1];
    const float* wd  = (const float*)d_in[2];
    const float* bd  = (const float*)d_in[3];
    const float* wu  = (const float*)d_in[4];
    const float* bu  = (const float*)d_in[5];
    const float* wsd = (const float*)d_in[6];
    const float* bsd = (const float*)d_in[7];
    const float* wsu = (const float*)d_in[8];
    const float* bsu = (const float*)d_in[9];
    float* out = (float*)d_out;

    // workspace layout (~79.2 MB):
    char* ws = (char*)d_ws;
    float* combine = (float*)(ws + 0);                 // 262,144
    int*   meta    = (int*)(ws + 262144);              // cnt[0..7], pbase[8..16]
    int*   sel     = (int*)(ws + 263168);              // 32,768
    int*   tokE    = (int*)(ws + 295936);              // 262,144
    bf16_t* Xbf    = (bf16_t*)(ws + 558080);           // 33,554,432
    bf16_t* H      = (bf16_t*)(ws + 34112512ull);      // 25600*512*2 = 26,214,400
    bf16_t* Wall   = (bf16_t*)(ws + 60326912ull);      // 18,874,368 (down; up overlay same size)

    gate_kernel<<<T_TOK / 4, 256, 0, stream>>>(x, gw, combine, sel, Xbf);
    build_kernel<<<1, 1024, 0, stream>>>(sel, meta, tokE);

    cvt_kernel<<<(4096 * D_IN / 8) / 256, 256, 0, stream>>>(wd, Wall, 4096 * D_IN / 8);
    cvt_kernel<<<(512 * D_IN / 8) / 256, 256, 0, stream>>>(wsd, Wall + (size_t)4096 * D_IN, 512 * D_IN / 8);

    down_kernel<<<dim3(4, 64, 9), 256, 0, stream>>>(Xbf, Wall, bd, bsd, combine, meta, tokE, H);

    // up weights overlay: [wu ; ws_u] -> bf16 [9*2048, 512]
    cvt_kernel<<<(8 * D_IN * D_BOT / 8) / 256, 256, 0, stream>>>(wu, Wall, 8 * D_IN * D_BOT / 8);
    cvt_kernel<<<(D_IN * D_BOT / 8) / 256, 256, 0, stream>>>(wsu, Wall + (size_t)8 * D_IN * D_BOT, D_IN * D_BOT / 8);

    initout_kernel<<<T_TOK, 256, 0, stream>>>(bu, bsu, combine, out);
    up_kernel<<<dim3(16, NROWS_H / 128), 256, 0, stream>>>(H, Wall, meta, tokE, out);
}

// Round 7
// 538.438 us; speedup vs baseline: 1.8481x; 1.0945x over previous
//
#include <hip/hip_runtime.h>
#include <hip/hip_bf16.h>

// ---------------- types / constants ----------------
typedef __bf16 bf16_t;
typedef __bf16 bf16x8 __attribute__((ext_vector_type(8)));
typedef float f32x4 __attribute__((ext_vector_type(4)));

#define T_TOK 8192
#define D_IN  2048
#define D_BOT 512
#define MAXTILES 192   // >= 8192/64 + 56

union U4B8 { uint4 u; bf16x8 b; };
__device__ __forceinline__ bf16x8 as_bf16x8(uint4 u) { U4B8 x; x.u = u; return x.b; }
__device__ __forceinline__ uint4 as_uint4(bf16x8 b) { U4B8 x; x.b = b; return x.u; }

typedef const __attribute__((address_space(1))) void gas_void;
typedef __attribute__((address_space(3))) void las_void;
__device__ __forceinline__ void async16(const void* g, void* l) {
    __builtin_amdgcn_global_load_lds((gas_void*)g, (las_void*)l, 16, 0, 0);
}

__device__ __forceinline__ uint4 ld_cvt8(const float* __restrict__ p) {
    f32x4 a0 = ((const f32x4*)p)[0];
    f32x4 a1 = ((const f32x4*)p)[1];
    bf16x8 v;
    v[0] = (bf16_t)a0[0]; v[1] = (bf16_t)a0[1]; v[2] = (bf16_t)a0[2]; v[3] = (bf16_t)a0[3];
    v[4] = (bf16_t)a1[0]; v[5] = (bf16_t)a1[1]; v[6] = (bf16_t)a1[2]; v[7] = (bf16_t)a1[3];
    return as_uint4(v);
}

__device__ __forceinline__ float gelu_f(float v) {
    return 0.5f * v * (1.0f + erff(v * 0.7071067811865476f));
}

__global__ __launch_bounds__(256) void cvt_kernel(const float* __restrict__ src,
                                                  bf16_t* __restrict__ dst, int n8) {
    const int i = blockIdx.x * 256 + threadIdx.x;
    if (i < n8) ((uint4*)dst)[i] = ld_cvt8(src + (size_t)i * 8);
}

// ---------------- gate: combine + sel + Xbf (fused x-convert; NO atomics) ----------------
__global__ __launch_bounds__(256) void gate_kernel(const float* __restrict__ x,
                                                   const float* __restrict__ gw,
                                                   float* __restrict__ combine,
                                                   int* __restrict__ sel,
                                                   bf16_t* __restrict__ Xbf) {
    const int wave = threadIdx.x >> 6, lane = threadIdx.x & 63;
    const int t = blockIdx.x * 4 + wave;
    const float* xrow = x + (size_t)t * D_IN;
    f32x4 xa[4][2];
#pragma unroll
    for (int c = 0; c < 4; ++c) {
        const float* p = xrow + c * 512 + lane * 8;
        xa[c][0] = ((const f32x4*)p)[0];
        xa[c][1] = ((const f32x4*)p)[1];
    }
#pragma unroll
    for (int c = 0; c < 4; ++c) {
        bf16x8 v;
#pragma unroll
        for (int j = 0; j < 4; ++j) { v[j] = (bf16_t)xa[c][0][j]; v[4 + j] = (bf16_t)xa[c][1][j]; }
        *(uint4*)(Xbf + (size_t)t * D_IN + c * 512 + lane * 8) = as_uint4(v);
    }
    float p[8];
#pragma unroll
    for (int e = 0; e < 8; ++e) {
        const float* gr = gw + e * D_IN;
        float s = 0.f;
#pragma unroll
        for (int c = 0; c < 4; ++c) {
            const float* q = gr + c * 512 + lane * 8;
            f32x4 g0 = ((const f32x4*)q)[0], g1 = ((const f32x4*)q)[1];
#pragma unroll
            for (int j = 0; j < 4; ++j) s += xa[c][0][j] * g0[j] + xa[c][1][j] * g1[j];
        }
#pragma unroll
        for (int off = 32; off > 0; off >>= 1) s += __shfl_xor(s, off, 64);
        p[e] = s;
    }
    float m = p[0];
#pragma unroll
    for (int e = 1; e < 8; ++e) m = fmaxf(m, p[e]);
    float sum = 0.f;
#pragma unroll
    for (int e = 0; e < 8; ++e) { p[e] = expf(p[e] - m); sum += p[e]; }
    const float inv = 1.0f / sum;
#pragma unroll
    for (int e = 0; e < 8; ++e) p[e] *= inv;
    int i0 = 0;
#pragma unroll
    for (int e = 1; e < 8; ++e) if (p[e] > p[i0]) i0 = e;
    int i1 = -1;
#pragma unroll
    for (int e = 0; e < 8; ++e) { if (e == i0) continue; if (i1 < 0 || p[e] > p[i1]) i1 = e; }
    const float rs = 1.0f / (p[i0] + p[i1]);
    if (lane < 8)
        combine[t * 8 + lane] = (lane == i0) ? p[i0] * rs : (lane == i1) ? p[i1] * rs : 0.0f;
    if (lane == 0) sel[t] = i0 | (i1 << 4);
}

// ---------------- deterministic list build: expert lists + pair bins + tile table ----------------
// meta: cnt[0..7]; ntiles@8; cntP[64]@64; tileP[192]@128; tileS[192]@320
__global__ __launch_bounds__(256) void build_kernel(const int* __restrict__ sel,
                                                    int* __restrict__ meta,
                                                    int* __restrict__ tokE,
                                                    int* __restrict__ tokP) {
    __shared__ unsigned short cAll[8][256];
    __shared__ unsigned short cP[64][256];
    const int tid = threadIdx.x;
#pragma unroll
    for (int e = 0; e < 8; ++e) cAll[e][tid] = 0;
#pragma unroll
    for (int p = 0; p < 64; ++p) cP[p][tid] = 0;
    __syncthreads();
    int sl[32];
#pragma unroll
    for (int j = 0; j < 32; ++j) sl[j] = sel[tid * 32 + j];
#pragma unroll
    for (int j = 0; j < 32; ++j) {
        const int e0 = sl[j] & 15, e1 = sl[j] >> 4;
        cAll[e0][tid]++; cAll[e1][tid]++; cP[e0 * 8 + e1][tid]++;
    }
    __syncthreads();
    if (tid < 8) {
        unsigned short* arr = cAll[tid];
        int run = 0;
        for (int i = 0; i < 256; ++i) { int v = arr[i]; arr[i] = (unsigned short)run; run += v; }
        meta[tid] = run;
    } else if (tid >= 64 && tid < 128) {
        unsigned short* arr = cP[tid - 64];
        int run = 0;
        for (int i = 0; i < 256; ++i) { int v = arr[i]; arr[i] = (unsigned short)run; run += v; }
        meta[64 + (tid - 64)] = run;
    }
    __syncthreads();
    if (tid == 0) {
        int nt = 0;
        for (int p = 0; p < 64; ++p) {
            const int c = meta[64 + p];
            for (int s = 0; s < c; s += 64) { meta[128 + nt] = p; meta[320 + nt] = s; ++nt; }
        }
        meta[8] = nt;
    }
#pragma unroll
    for (int j = 0; j < 32; ++j) {
        const int t = tid * 32 + j, e0 = sl[j] & 15, e1 = sl[j] >> 4;
        const int p0 = cAll[e0][tid]++;  tokE[e0 * 8192 + p0] = t;           // rank 0
        const int p1 = cAll[e1][tid]++;  tokE[e1 * 8192 + p1] = t | 65536;   // rank 1
        const int q  = cP[e0 * 8 + e1][tid]++;  tokP[(e0 * 8 + e1) * 8192 + q] = t;
    }
}

// ---------------- sparse down: Ht[t][rank][:] = gelu(X[t]@W_e^T + b) * combine ----------------
// grid (64, 4, 9): x = m-tile (XCD locality), y = n-tile, z = expert (8 = shared -> Ht[t][2]).
__global__ __launch_bounds__(256) void down_kernel(const bf16_t* __restrict__ Xbf,
                                                   const bf16_t* __restrict__ Wall,
                                                   const float* __restrict__ Bd,
                                                   const float* __restrict__ Bsd,
                                                   const float* __restrict__ combine,
                                                   const int* __restrict__ meta,
                                                   const int* __restrict__ tokE,
                                                   bf16_t* __restrict__ Ht) {
    __shared__ uint4 As4[128 * 8];
    __shared__ uint4 Bs4[128 * 8];
    const int e = blockIdx.z;
    const int count = (e < 8) ? meta[e] : T_TOK;
    const int m0 = blockIdx.x * 128;
    if (m0 >= count) return;
    const int tid = threadIdx.x, lane = tid & 63, wv = tid >> 6;
    const int wm = wv >> 1, wn = wv & 1;
    const int tile_n = blockIdx.y * 128;
    const int gB = (lane & 7) ^ ((lane >> 3) & 7);

    const bf16_t* aAddr[4];
    const bf16_t* bAddr[4];
#pragma unroll
    for (int j = 0; j < 4; ++j) {
        const int rr = (wv * 4 + j) * 8 + (lane >> 3);
        int gi = m0 + rr; if (gi > count - 1) gi = count - 1;
        const int t = (e < 8) ? (tokE[e * 8192 + gi] & 0xFFFF) : gi;
        aAddr[j] = Xbf + (size_t)t * D_IN + gB * 8;
        bAddr[j] = Wall + (size_t)(e * 512 + tile_n + rr) * D_IN + gB * 8;
    }

    f32x4 acc[4][4];
#pragma unroll
    for (int i = 0; i < 4; ++i)
#pragma unroll
        for (int j = 0; j < 4; ++j) acc[i][j] = (f32x4){0.f, 0.f, 0.f, 0.f};

    for (int kt = 0; kt < D_IN / 64; ++kt) {
        const int k0 = kt * 64;
#pragma unroll
        for (int j = 0; j < 4; ++j) {
            const int c = wv * 4 + j;
            async16(aAddr[j] + k0, &As4[c * 64]);
            async16(bAddr[j] + k0, &Bs4[c * 64]);
        }
        __syncthreads();
#pragma unroll
        for (int ks = 0; ks < 2; ++ks) {
            bf16x8 af[4], bfr[4];
#pragma unroll
            for (int i = 0; i < 4; ++i) {
                const int ar = wm * 64 + i * 16 + (lane & 15);
                af[i] = as_bf16x8(As4[ar * 8 + ((ks * 4 + (lane >> 4)) ^ (lane & 7))]);
                const int br = wn * 64 + i * 16 + (lane & 15);
                bfr[i] = as_bf16x8(Bs4[br * 8 + ((ks * 4 + (lane >> 4)) ^ (lane & 7))]);
            }
#pragma unroll
            for (int mi = 0; mi < 4; ++mi)
#pragma unroll
                for (int nj = 0; nj < 4; ++nj)
                    acc[mi][nj] = __builtin_amdgcn_mfma_f32_16x16x32_bf16(
                        af[mi], bfr[nj], acc[mi][nj], 0, 0, 0);
        }
        __syncthreads();
    }

#pragma unroll
    for (int nj = 0; nj < 4; ++nj) {
        const int nn = tile_n + wn * 64 + nj * 16 + (lane & 15);   // 0..511
        const float bias = (e < 8) ? Bd[e * 512 + nn] : Bsd[nn];
#pragma unroll
        for (int mi = 0; mi < 4; ++mi) {
            const int g0 = m0 + wm * 64 + mi * 16 + ((lane >> 4) << 2);
#pragma unroll
            for (int r = 0; r < 4; ++r) {
                const int gi = g0 + r;
                if (gi >= count) continue;
                if (e < 8) {
                    const int entry = tokE[e * 8192 + gi];
                    const int t = entry & 0xFFFF, rank = entry >> 16;
                    const float v = gelu_f(acc[mi][nj][r] + bias) * combine[t * 8 + e];
                    Ht[(size_t)t * 1536 + rank * 512 + nn] = (bf16_t)v;
                } else {
                    Ht[(size_t)gi * 1536 + 1024 + nn] = (bf16_t)gelu_f(acc[mi][nj][r] + bias);
                }
            }
        }
    }
}

// ---------------- pair-grouped up: Out[t,:] = Ht[t,:]@B_pair^T + c@bu + bs_u (direct store) ----
// grid (192, 16): x = m-tile from tile table, y = n-tile.
__global__ __launch_bounds__(256) void up_kernel(const bf16_t* __restrict__ Ht,
                                                 const bf16_t* __restrict__ Wup,
                                                 const float* __restrict__ Bu,
                                                 const float* __restrict__ Bsu,
                                                 const float* __restrict__ combine,
                                                 const int* __restrict__ meta,
                                                 const int* __restrict__ tokP,
                                                 float* __restrict__ Out) {
    __shared__ uint4 As4[64 * 8];
    __shared__ uint4 Bs4[128 * 8];
    const int yt = blockIdx.x;
    if (yt >= meta[8]) return;
    const int p = meta[128 + yt], s = meta[320 + yt];
    const int e0 = p >> 3, e1 = p & 7;
    const int cntP = meta[64 + p];
    const int tid = threadIdx.x, lane = tid & 63, wv = tid >> 6;
    const int wm = wv >> 1, wn = wv & 1;
    const int tile_n = blockIdx.y * 128;
    const int gB = (lane & 7) ^ ((lane >> 3) & 7);

    const bf16_t* aAddr[2];
#pragma unroll
    for (int j = 0; j < 2; ++j) {
        const int rr = (wv * 2 + j) * 8 + (lane >> 3);
        int gi = s + rr; if (gi > cntP - 1) gi = cntP - 1;
        const int t = tokP[p * 8192 + gi];
        aAddr[j] = Ht + (size_t)t * 1536 + gB * 8;
    }
    size_t bRow[4];
#pragma unroll
    for (int j = 0; j < 4; ++j) {
        const int rr = (wv * 4 + j) * 8 + (lane >> 3);
        bRow[j] = (size_t)(tile_n + rr) * D_BOT + gB * 8;
    }

    f32x4 acc[2][4];
#pragma unroll
    for (int i = 0; i < 2; ++i)
#pragma unroll
        for (int j = 0; j < 4; ++j) acc[i][j] = (f32x4){0.f, 0.f, 0.f, 0.f};

    for (int kt = 0; kt < 24; ++kt) {
        const int seg = kt >> 3;
        const int slot = (seg == 0) ? e0 : (seg == 1) ? e1 : 8;
        const bf16_t* wbase = Wup + (size_t)slot * (D_IN * D_BOT) + (kt & 7) * 64;
#pragma unroll
        for (int j = 0; j < 2; ++j)
            async16(aAddr[j] + kt * 64, &As4[(wv * 2 + j) * 64]);
#pragma unroll
        for (int j = 0; j < 4; ++j)
            async16(wbase + bRow[j], &Bs4[(wv * 4 + j) * 64]);
        __syncthreads();
#pragma unroll
        for (int ks = 0; ks < 2; ++ks) {
            bf16x8 af[2], bfr[4];
#pragma unroll
            for (int i = 0; i < 2; ++i) {
                const int ar = wm * 32 + i * 16 + (lane & 15);
                af[i] = as_bf16x8(As4[ar * 8 + ((ks * 4 + (lane >> 4)) ^ (lane & 7))]);
            }
#pragma unroll
            for (int i = 0; i < 4; ++i) {
                const int br = wn * 64 + i * 16 + (lane & 15);
                bfr[i] = as_bf16x8(Bs4[br * 8 + ((ks * 4 + (lane >> 4)) ^ (lane & 7))]);
            }
#pragma unroll
            for (int mi = 0; mi < 2; ++mi)
#pragma unroll
                for (int nj = 0; nj < 4; ++nj)
                    acc[mi][nj] = __builtin_amdgcn_mfma_f32_16x16x32_bf16(
                        af[mi], bfr[nj], acc[mi][nj], 0, 0, 0);
        }
        __syncthreads();
    }

#pragma unroll
    for (int nj = 0; nj < 4; ++nj) {
        const int d = tile_n + wn * 64 + nj * 16 + (lane & 15);    // 0..2047
        const float bu0 = Bu[e0 * D_IN + d], bu1 = Bu[e1 * D_IN + d], bs = Bsu[d];
#pragma unroll
        for (int mi = 0; mi < 2; ++mi) {
            const int r0 = wm * 32 + mi * 16 + ((lane >> 4) << 2);
#pragma unroll
            for (int r = 0; r < 4; ++r) {
                const int gi = s + r0 + r;
                if (gi >= cntP) continue;
                const int t = tokP[p * 8192 + gi];
                const float c0 = combine[t * 8 + e0], c1 = combine[t * 8 + e1];
                Out[(size_t)t * D_IN + d] = acc[mi][nj][r] + c0 * bu0 + c1 * bu1 + bs;
            }
        }
    }
}

// ---------------- launch ----------------
extern "C" void kernel_launch(void* const* d_in, const int* in_sizes, int n_in,
                              void* d_out, int out_size, void* d_ws, size_t ws_size,
                              hipStream_t stream) {
    const float* x   = (const float*)d_in[0];
    const float* gw  = (const float*)d_in[1];
    const float* wd  = (const float*)d_in[2];
    const float* bd  = (const float*)d_in[3];
    const float* wu  = (const float*)d_in[4];
    const float* bu  = (const float*)d_in[5];
    const float* wsd = (const float*)d_in[6];
    const float* bsd = (const float*)d_in[7];
    const float* wsu = (const float*)d_in[8];
    const float* bsu = (const float*)d_in[9];
    float* out = (float*)d_out;

    // workspace layout (~80.3 MB):
    char* ws = (char*)d_ws;
    float* combine = (float*)(ws + 0);                 // 262,144
    int*   meta    = (int*)(ws + 262144);              // 4 KB: cnt[8], ntiles@8, cntP@64, tileP@128, tileS@320
    int*   sel     = (int*)(ws + 266240);              // 32,768
    int*   tokE    = (int*)(ws + 299008);              // 8*8192*4 = 262,144
    int*   tokP    = (int*)(ws + 561152);              // 64*8192*4 = 2,097,152
    bf16_t* Xbf    = (bf16_t*)(ws + 2658304);          // 33,554,432
    bf16_t* Ht     = (bf16_t*)(ws + 36212736ull);      // 8192*1536*2 = 25,165,824
    bf16_t* Wall   = (bf16_t*)(ws + 61378560ull);      // 18,874,368 (down; up overlay 9.4 MB)

    gate_kernel<<<T_TOK / 4, 256, 0, stream>>>(x, gw, combine, sel, Xbf);
    build_kernel<<<1, 256, 0, stream>>>(sel, meta, tokE, tokP);

    cvt_kernel<<<(4096 * D_IN / 8) / 256, 256, 0, stream>>>(wd, Wall, 4096 * D_IN / 8);
    cvt_kernel<<<(512 * D_IN / 8) / 256, 256, 0, stream>>>(wsd, Wall + (size_t)4096 * D_IN, 512 * D_IN / 8);

    down_kernel<<<dim3(64, 4, 9), 256, 0, stream>>>(Xbf, Wall, bd, bsd, combine, meta, tokE, Ht);

    // up weights overlay: [wu ; ws_u] -> bf16 [9*2048, 512]
    cvt_kernel<<<(8 * D_IN * D_BOT / 8) / 256, 256, 0, stream>>>(wu, Wall, 8 * D_IN * D_BOT / 8);
    cvt_kernel<<<(D_IN * D_BOT / 8) / 256, 256, 0, stream>>>(wsu, Wall + (size_t)8 * D_IN * D_BOT, D_IN * D_BOT / 8);

    up_kernel<<<dim3(MAXTILES, 16), 256, 0, stream>>>(Ht, Wall, bu, bsu, combine, meta, tokP, out);
}